// Round 8
// baseline (85.059 us; speedup 1.0000x reference)
//
#include <hip/hip_runtime.h>
#include <hip/hip_bf16.h>
#include <hip/hip_fp16.h>
#include <cstdint>
#include <cstddef>

#define B_TOK 8192
#define NIN   512
#define NOUTD 512
#define NEXP  32

typedef _Float16 half8 __attribute__((ext_vector_type(8)));
typedef _Float16 half4 __attribute__((ext_vector_type(4)));
typedef float f32x4 __attribute__((ext_vector_type(4)));

// ---------------- fast-path workspace layout (bytes) ----------------
#define F_XF16  0u          // f16 [8192][512]        = 8 MB
#define F_PART  8388608u    // f32 [4][8192][32]      = 4 MB (gate partials)
#define F_CNT   12582912u   // i32 [2][32]
#define F_GTOK  12583424u   // i32 [2][32][8192]      = 2 MB
#define F_GW    14680576u   // f32 [2][32][8192]      = 2 MB
#define F_NEED  16777728u

// ---------------- fallback (round-1) workspace layout ----------------
#define WS_LOGITS 0u
#define WS_TKIDX  (1u<<20)
#define WS_TKW    (WS_TKIDX + 65536u)
#define WS_CTRS   (WS_TKW + 65536u)
#define WS_CURS   (WS_CTRS + 256u)
#define WS_TILEC  (WS_CURS + 256u)
#define WS_OFFS   (WS_TILEC + 256u)
#define WS_TILES  (WS_OFFS + 256u)
#define WS_GTOK   (WS_TILES + 4096u)
#define WS_GW     (WS_GTOK + 65536u)

__device__ __forceinline__ void gload_lds16(const void* gsrc, void* ldst) {
    __builtin_amdgcn_global_load_lds((const __attribute__((address_space(1))) uint32_t*)gsrc,
                                     (__attribute__((address_space(3))) uint32_t*)ldst,
                                     16, 0, 0);
}

// ============ FAST K1: gate GEMM split-K=4 + xf16; zeroes counts ============
// grid 512 = 128 token-tiles x 4 k-slices; part[sl][tok][e] (no bias)
__global__ __launch_bounds__(256) void k_prep(const float* __restrict__ x,
                                              const float* __restrict__ Wg,
                                              float* __restrict__ part,
                                              int* __restrict__ counts,
                                              _Float16* __restrict__ xf16) {
    __shared__ float xs[64 * 68];
    __shared__ float wgs[64 * 32];
    const int t = threadIdx.x;
    if (blockIdx.x == 0 && t < 64) counts[t] = 0;
    const int tt = blockIdx.x >> 2, sl = blockIdx.x & 3;
    const int b0 = tt * 64;
    const int kbase = sl * 128;
    const int tok = t >> 2;
    const int eg  = (t & 3) * 8;

    float acc[8];
#pragma unroll
    for (int i = 0; i < 8; i++) acc[i] = 0.f;

    for (int ksi = 0; ksi < 2; ksi++) {
        const int k0 = kbase + ksi * 64;
#pragma unroll
        for (int i = 0; i < 4; i++) {
            int idx = t + i * 256;
            int tr = idx >> 4, kq = idx & 15;
            float4 v = *(const float4*)&x[(size_t)(b0 + tr) * NIN + k0 + kq * 4];
            *(float4*)&xs[tr * 68 + kq * 4] = v;
            half4 hv = {(_Float16)v.x, (_Float16)v.y, (_Float16)v.z, (_Float16)v.w};
            *(half4*)&xf16[(size_t)(b0 + tr) * NIN + k0 + kq * 4] = hv;
        }
#pragma unroll
        for (int i = 0; i < 2; i++) {
            int idx = t + i * 256;
            int r = idx >> 3, cq = idx & 7;
            float4 v = *(const float4*)&Wg[(size_t)(k0 + r) * NEXP + cq * 4];
            *(float4*)&wgs[r * 32 + cq * 4] = v;
        }
        __syncthreads();
#pragma unroll
        for (int kk = 0; kk < 64; kk++) {
            float a = xs[tok * 68 + kk];
            float4 b1 = *(const float4*)&wgs[kk * 32 + eg];
            float4 b2 = *(const float4*)&wgs[kk * 32 + eg + 4];
            acc[0] = fmaf(a, b1.x, acc[0]);
            acc[1] = fmaf(a, b1.y, acc[1]);
            acc[2] = fmaf(a, b1.z, acc[2]);
            acc[3] = fmaf(a, b1.w, acc[3]);
            acc[4] = fmaf(a, b2.x, acc[4]);
            acc[5] = fmaf(a, b2.y, acc[5]);
            acc[6] = fmaf(a, b2.z, acc[6]);
            acc[7] = fmaf(a, b2.w, acc[7]);
        }
        __syncthreads();
    }
    float4 o1 = {acc[0], acc[1], acc[2], acc[3]};
    float4 o2 = {acc[4], acc[5], acc[6], acc[7]};
    size_t ob = ((size_t)sl * B_TOK + b0 + tok) * NEXP + eg;
    *(float4*)&part[ob] = o1;
    *(float4*)&part[ob + 4] = o2;
}

// ============ FAST K2: sum partials + softmax + top2 + scatter + aux ============
// 64 blocks x 128 tokens
__global__ __launch_bounds__(256) void k_top2_route(const float* __restrict__ part,
                                                    const float* __restrict__ bg,
                                                    int* __restrict__ counts,
                                                    int* __restrict__ gtok,
                                                    float* __restrict__ gw,
                                                    float* __restrict__ aux) {
    __shared__ float sacc[128 * 33];
    __shared__ int lc[64];
    __shared__ int lbase[64];
    const int t = threadIdx.x;
    const int b0 = blockIdx.x * 128;
    if (blockIdx.x == 0 && t == 0) aux[0] = 0.0f;

    for (int sl = 0; sl < 4; sl++) {
#pragma unroll
        for (int i = 0; i < 4; i++) {
            int idx = t + i * 256;            // 0..1023
            int tok = idx >> 3, ef = (idx & 7) * 4;
            float4 v = *(const float4*)&part[((size_t)sl * B_TOK + b0 + tok) * NEXP + ef];
            float* d = &sacc[tok * 33 + ef];
            if (sl == 0) { d[0] = v.x; d[1] = v.y; d[2] = v.z; d[3] = v.w; }
            else         { d[0] += v.x; d[1] += v.y; d[2] += v.z; d[3] += v.w; }
        }
    }
    if (t < 64) lc[t] = 0;
    __syncthreads();

    float w0 = 0.f, w1 = 0.f;
    int i0 = 0, i1 = 0;
    const bool act = t < 128;
    if (act) {
        float v[32];
#pragma unroll
        for (int e = 0; e < NEXP; e++) v[e] = sacc[t * 33 + e] + bg[e];
        float m = v[0];
#pragma unroll
        for (int e = 1; e < NEXP; e++) m = fmaxf(m, v[e]);
        float s = 0.f;
        float v0 = -3.0e38f, v1 = -3.0e38f;
#pragma unroll
        for (int e = 0; e < NEXP; e++) {
            float val = v[e];
            s += expf(val - m);
            if (val > v0) { v1 = v0; i1 = i0; v0 = val; i0 = e; }
            else if (val > v1) { v1 = val; i1 = e; }
        }
        float inv = 1.f / s;
        w0 = expf(v0 - m) * inv;
        w1 = expf(v1 - m) * inv;
    }
    int r0 = 0, r1 = 0;
    if (act) {
        r0 = atomicAdd(&lc[i0], 1);
        r1 = atomicAdd(&lc[32 + i1], 1);
    }
    __syncthreads();
    if (t < 64) lbase[t] = (lc[t] > 0) ? atomicAdd(&counts[t], lc[t]) : 0;
    __syncthreads();
    if (act) {
        int p0 = lbase[i0] + r0;
        int p1 = lbase[32 + i1] + r1;
        gtok[i0 * B_TOK + p0] = b0 + t;          gw[i0 * B_TOK + p0] = w0;
        gtok[(32 + i1) * B_TOK + p1] = b0 + t;   gw[(32 + i1) * B_TOK + p1] = w1;
    }
}

// ============ FAST K3/K4: grouped expert GEMM, MFMA f16, 128x128, 8 waves ============
// 512 threads: wave grid 2x4, each wave computes 64 tok x 32 n.
// A staged from xf16 via global_load_lds; B staged from We (f32) via reg-cvt->LDS.
template <int ACC>
__global__ __launch_bounds__(512) void k_expert16(const _Float16* __restrict__ xf16,
                                                  const float* __restrict__ We,
                                                  const float* __restrict__ be,
                                                  const int* __restrict__ counts,
                                                  const int* __restrict__ gtok,
                                                  const float* __restrict__ gw,
                                                  float* __restrict__ out,
                                                  int round) {
    __shared__ _Float16 sA[2][128 * 32];   // [buf][token-row][k], 16B slots XOR-swizzled by row&3
    __shared__ _Float16 sB[2][128 * 32];   // [buf][n-row][k], same swizzle
    __shared__ int   stok[128];
    __shared__ float sw[128];
    __shared__ float sbe[128];
    __shared__ int   pfx[33];

    const int t = threadIdx.x;
    const int lane = t & 63, wid = t >> 6;          // 8 waves
    const int wr = wid >> 2, wc = wid & 3;          // 2 x 4
    const int srow = t >> 2;                        // A staging row 0..127
    const int ksw = (((t & 3) ^ (srow & 3)) * 8);   // A swizzled k-offset (elements)
    const int kp = t & 15, nq = t >> 4;             // B staging: k-pair 0..15, n-quad 0..31
    const int kk = kp * 2;
    const int bslot = kk >> 3, bwithin = kk & 7;    // B LDS slot/element within slot
    const int g = lane >> 4, c16 = lane & 15;

    if (t == 0) {
        int a = 0;
#pragma unroll
        for (int e = 0; e < NEXP; e++) { pfx[e] = a; a += (counts[round * 32 + e] + 127) >> 7; }
        pfx[32] = a;
    }
    __syncthreads();
    const int ntiles = pfx[32] * 4;

    for (int tile = blockIdx.x; tile < ntiles; tile += gridDim.x) {
        const int rt = tile >> 2, ct = tile & 3, nb = ct * 128;
        int e = 0;
        while (pfx[e + 1] <= rt) e++;
        const int jt = rt - pfx[e];
        const int cnt = counts[round * 32 + e];
        const int base = (round * 32 + e) * B_TOK + jt * 128;
        const int valid = min(128, cnt - jt * 128);

        if (t < 128) {
            int rr = min(t, valid - 1);
            stok[t] = gtok[base + rr];
            sw[t]   = gw[base + rr];
            sbe[t]  = be[e * NOUTD + nb + t];
        }
        __syncthreads();

        f32x4 acc[4][2];
#pragma unroll
        for (int m = 0; m < 4; m++)
#pragma unroll
            for (int n = 0; n < 2; n++) acc[m][n] = (f32x4){0.f, 0.f, 0.f, 0.f};

        // B source: We[e][k][nb + nq*4 .. +3], rows k = k0 + kk, k0 + kk + 1
        const float* WB = We + (size_t)e * NIN * NOUTD + nb + nq * 4;
        const int sbase = (wid * 16) * 32;   // A staging wave-uniform LDS base

        // ---- prologue: stage k0=0 into buf 0 ----
        gload_lds16(xf16 + (size_t)stok[srow] * NIN + ksw, &sA[0][sbase]);
        {
            float4 v0 = *(const float4*)&WB[(size_t)kk * NOUTD];
            float4 v1 = *(const float4*)&WB[(size_t)(kk + 1) * NOUTD];
            float a0[4] = {v0.x, v0.y, v0.z, v0.w};
            float a1[4] = {v1.x, v1.y, v1.z, v1.w};
#pragma unroll
            for (int j = 0; j < 4; j++) {
                int n = nq * 4 + j;
                union { _Float16 h[2]; uint32_t u; } pk;
                pk.h[0] = (_Float16)a0[j];
                pk.h[1] = (_Float16)a1[j];
                *(uint32_t*)&sB[0][n * 32 + ((bslot ^ (n & 3)) * 8) + bwithin] = pk.u;
            }
        }
        __syncthreads();

        int cur = 0;
        for (int k0 = 0; k0 < NIN; k0 += 32) {
            const bool more = (k0 + 32) < NIN;
            float a0[4], a1[4];
            if (more) {
                // issue next-step loads early (T14): A direct-to-LDS, B to regs
                gload_lds16(xf16 + (size_t)stok[srow] * NIN + k0 + 32 + ksw,
                            &sA[cur ^ 1][sbase]);
                float4 v0 = *(const float4*)&WB[(size_t)(k0 + 32 + kk) * NOUTD];
                float4 v1 = *(const float4*)&WB[(size_t)(k0 + 32 + kk + 1) * NOUTD];
                a0[0] = v0.x; a0[1] = v0.y; a0[2] = v0.z; a0[3] = v0.w;
                a1[0] = v1.x; a1[1] = v1.y; a1[2] = v1.z; a1[3] = v1.w;
            }

            half8 fa[4], fb[2];
#pragma unroll
            for (int m = 0; m < 4; m++) {
                int ar = wr * 64 + m * 16 + c16;
                fa[m] = *(const half8*)&sA[cur][ar * 32 + ((g ^ (ar & 3)) * 8)];
            }
#pragma unroll
            for (int n = 0; n < 2; n++) {
                int br = wc * 32 + n * 16 + c16;
                fb[n] = *(const half8*)&sB[cur][br * 32 + ((g ^ (br & 3)) * 8)];
            }
#pragma unroll
            for (int m = 0; m < 4; m++)
#pragma unroll
                for (int n = 0; n < 2; n++)
                    acc[m][n] = __builtin_amdgcn_mfma_f32_16x16x32_f16(fa[m], fb[n], acc[m][n], 0, 0, 0);

            if (more) {
                // write-late: convert and store next B tile (loads have had MFMA time to land)
#pragma unroll
                for (int j = 0; j < 4; j++) {
                    int n = nq * 4 + j;
                    union { _Float16 h[2]; uint32_t u; } pk;
                    pk.h[0] = (_Float16)a0[j];
                    pk.h[1] = (_Float16)a1[j];
                    *(uint32_t*)&sB[cur ^ 1][n * 32 + ((bslot ^ (n & 3)) * 8) + bwithin] = pk.u;
                }
            }
            __syncthreads();
            cur ^= 1;
        }

#pragma unroll
        for (int m = 0; m < 4; m++) {
#pragma unroll
            for (int q = 0; q < 4; q++) {
                int lr = wr * 64 + m * 16 + g * 4 + q;
                if (lr < valid) {
                    float w = sw[lr];
                    size_t ob = (size_t)stok[lr] * NOUTD + nb + wc * 32 + c16;
#pragma unroll
                    for (int n = 0; n < 2; n++) {
                        float v = fmaxf(acc[m][n][q] + sbe[wc * 32 + n * 16 + c16], 0.f) * w;
                        float* op = &out[ob + n * 16];
                        if (ACC) v += *op;
                        *op = v;
                    }
                }
            }
        }
        __syncthreads();
    }
}

// =====================================================================
// ==================== fallback (round-1, fp32) path ==================
// =====================================================================
__global__ __launch_bounds__(256) void k_gate(const float* __restrict__ x,
                                              const float* __restrict__ Wg,
                                              const float* __restrict__ bg,
                                              float* __restrict__ logits) {
    __shared__ float xs[64 * 68];
    __shared__ float wgs[64 * 32];
    const int t = threadIdx.x;
    const int b0 = blockIdx.x * 64;
    const int tok = t >> 2;
    const int eg  = (t & 3) * 8;
    float acc[8];
#pragma unroll
    for (int i = 0; i < 8; i++) acc[i] = 0.f;
    for (int k0 = 0; k0 < NIN; k0 += 64) {
#pragma unroll
        for (int i = 0; i < 4; i++) {
            int idx = t + i * 256;
            int tr = idx >> 4, kq = idx & 15;
            float4 v = *(const float4*)&x[(size_t)(b0 + tr) * NIN + k0 + kq * 4];
            *(float4*)&xs[tr * 68 + kq * 4] = v;
        }
#pragma unroll
        for (int i = 0; i < 2; i++) {
            int idx = t + i * 256;
            int r = idx >> 3, cq = idx & 7;
            float4 v = *(const float4*)&Wg[(size_t)(k0 + r) * NEXP + cq * 4];
            *(float4*)&wgs[r * 32 + cq * 4] = v;
        }
        __syncthreads();
#pragma unroll
        for (int kk = 0; kk < 64; kk++) {
            float a = xs[tok * 68 + kk];
            float4 b1 = *(const float4*)&wgs[kk * 32 + eg];
            float4 b2 = *(const float4*)&wgs[kk * 32 + eg + 4];
            acc[0] = fmaf(a, b1.x, acc[0]);
            acc[1] = fmaf(a, b1.y, acc[1]);
            acc[2] = fmaf(a, b1.z, acc[2]);
            acc[3] = fmaf(a, b1.w, acc[3]);
            acc[4] = fmaf(a, b2.x, acc[4]);
            acc[5] = fmaf(a, b2.y, acc[5]);
            acc[6] = fmaf(a, b2.z, acc[6]);
            acc[7] = fmaf(a, b2.w, acc[7]);
        }
        __syncthreads();
    }
    float4 o1, o2;
    o1.x = acc[0] + bg[eg + 0]; o1.y = acc[1] + bg[eg + 1];
    o1.z = acc[2] + bg[eg + 2]; o1.w = acc[3] + bg[eg + 3];
    o2.x = acc[4] + bg[eg + 4]; o2.y = acc[5] + bg[eg + 5];
    o2.z = acc[6] + bg[eg + 6]; o2.w = acc[7] + bg[eg + 7];
    size_t ob = (size_t)(b0 + tok) * NEXP + eg;
    *(float4*)&logits[ob] = o1;
    *(float4*)&logits[ob + 4] = o2;
}

__global__ __launch_bounds__(256) void k_top2(const float* __restrict__ logits,
                                              int* __restrict__ tkidx,
                                              float* __restrict__ tkw,
                                              int* __restrict__ counts) {
    __shared__ int lc[64];
    const int t = threadIdx.x;
    const int b = blockIdx.x * 256 + t;
    if (t < 64) lc[t] = 0;
    __syncthreads();
    float v[32];
#pragma unroll
    for (int i = 0; i < 8; i++) {
        float4 q = *(const float4*)&logits[(size_t)b * NEXP + i * 4];
        v[i * 4 + 0] = q.x; v[i * 4 + 1] = q.y; v[i * 4 + 2] = q.z; v[i * 4 + 3] = q.w;
    }
    float m = v[0];
#pragma unroll
    for (int e = 1; e < NEXP; e++) m = fmaxf(m, v[e]);
    float s = 0.f;
#pragma unroll
    for (int e = 0; e < NEXP; e++) s += expf(v[e] - m);
    float v0 = -3.0e38f, v1 = -3.0e38f;
    int i0 = 0, i1 = 0;
#pragma unroll
    for (int e = 0; e < NEXP; e++) {
        float val = v[e];
        if (val > v0) { v1 = v0; i1 = i0; v0 = val; i0 = e; }
        else if (val > v1) { v1 = val; i1 = e; }
    }
    float inv = 1.f / s;
    tkidx[b * 2 + 0] = i0; tkidx[b * 2 + 1] = i1;
    tkw[b * 2 + 0] = expf(v0 - m) * inv; tkw[b * 2 + 1] = expf(v1 - m) * inv;
    atomicAdd(&lc[i0], 1);
    atomicAdd(&lc[32 + i1], 1);
    __syncthreads();
    if (t < 64 && lc[t] > 0) atomicAdd(&counts[t], lc[t]);
}

__global__ __launch_bounds__(64) void k_build(const int* __restrict__ counts,
                                              int* __restrict__ offs,
                                              int* __restrict__ curs,
                                              int2* __restrict__ tiles,
                                              int* __restrict__ tilec,
                                              float* __restrict__ aux) {
    __shared__ int c[64];
    __shared__ int o[64];
    const int t = threadIdx.x;
    c[t] = counts[t];
    __syncthreads();
    if (t == 0) {
        int off = 0;
        for (int i = 0; i < 64; i++) {
            if ((i & 31) == 0) off = 0;
            o[i] = off;
            off += c[i];
        }
        aux[0] = 0.0f;
    }
    __syncthreads();
    offs[t] = o[t];
    curs[t] = o[t];
    if (t < 2) {
        int tc = 0;
        for (int e = 0; e < NEXP; e++) {
            int cnt = c[t * 32 + e];
            int nt = (cnt + 63) >> 6;
            for (int j = 0; j < nt; j++) tiles[t * 256 + tc++] = make_int2(e, j);
        }
        tilec[t] = tc;
    }
}

__global__ __launch_bounds__(256) void k_scatter(const int* __restrict__ tkidx,
                                                 const float* __restrict__ tkw,
                                                 int* __restrict__ curs,
                                                 int* __restrict__ gtok,
                                                 float* __restrict__ gw) {
    __shared__ int lc[64];
    __shared__ int lbase[64];
    const int t = threadIdx.x;
    const int b = blockIdx.x * 256 + t;
    if (t < 64) lc[t] = 0;
    __syncthreads();
    int i0 = tkidx[b * 2 + 0], i1 = tkidx[b * 2 + 1];
    int r0 = atomicAdd(&lc[i0], 1);
    int r1 = atomicAdd(&lc[32 + i1], 1);
    __syncthreads();
    if (t < 64) lbase[t] = (lc[t] > 0) ? atomicAdd(&curs[t], lc[t]) : 0;
    __syncthreads();
    int p0 = lbase[i0] + r0;
    int p1 = lbase[32 + i1] + r1;
    gtok[p0] = b;          gw[p0] = tkw[b * 2 + 0];
    gtok[8192 + p1] = b;   gw[8192 + p1] = tkw[b * 2 + 1];
}

template <int ACC>
__global__ __launch_bounds__(256) void k_expert(const float* __restrict__ x,
                                                const float* __restrict__ We,
                                                const float* __restrict__ be,
                                                const int* __restrict__ counts,
                                                const int* __restrict__ offs,
                                                const int2* __restrict__ tiles,
                                                const int* __restrict__ tilec,
                                                const int* __restrict__ gtok,
                                                const float* __restrict__ gw,
                                                float* __restrict__ out,
                                                int round) {
    __shared__ float xsT[32 * 68];
    __shared__ float wsd[32 * 64];
    __shared__ int   stok[64];
    __shared__ float sw[64];
    const int t = threadIdx.x;
    const int tx = t & 15, ty = t >> 4;
    const int ntiles = tilec[round] * 8;
    for (int tile = blockIdx.x; tile < ntiles; tile += gridDim.x) {
        int rt = tile >> 3, ct = tile & 7;
        int2 td = tiles[round * 256 + rt];
        int e = td.x, jt = td.y;
        int cnt = counts[round * 32 + e];
        int base = offs[round * 32 + e] + jt * 64;
        int valid = min(64, cnt - jt * 64);
        if (t < 64) {
            int rr = min(t, valid - 1);
            stok[t] = gtok[round * 8192 + base + rr];
            sw[t]   = gw  [round * 8192 + base + rr];
        }
        __syncthreads();
        float acc[16];
#pragma unroll
        for (int i = 0; i < 16; i++) acc[i] = 0.f;
        const float* Wb = We + (size_t)e * NIN * NOUTD + ct * 64;
        for (int k0 = 0; k0 < NIN; k0 += 32) {
#pragma unroll
            for (int i = 0; i < 2; i++) {
                int idx = t + i * 256;
                int tr = idx >> 3, kq = idx & 7;
                float4 v = *(const float4*)&x[(size_t)stok[tr] * NIN + k0 + kq * 4];
                xsT[(kq * 4 + 0) * 68 + tr] = v.x;
                xsT[(kq * 4 + 1) * 68 + tr] = v.y;
                xsT[(kq * 4 + 2) * 68 + tr] = v.z;
                xsT[(kq * 4 + 3) * 68 + tr] = v.w;
            }
#pragma unroll
            for (int i = 0; i < 2; i++) {
                int idx = t + i * 256;
                int r = idx >> 4, cq = idx & 15;
                *(float4*)&wsd[r * 64 + cq * 4] =
                    *(const float4*)&Wb[(size_t)(k0 + r) * NOUTD + cq * 4];
            }
            __syncthreads();
#pragma unroll
            for (int kk = 0; kk < 32; kk++) {
                float4 a  = *(const float4*)&xsT[kk * 68 + ty * 4];
                float4 bv = *(const float4*)&wsd[kk * 64 + tx * 4];
                float av[4] = {a.x, a.y, a.z, a.w};
                float bb[4] = {bv.x, bv.y, bv.z, bv.w};
#pragma unroll
                for (int i = 0; i < 4; i++)
#pragma unroll
                    for (int j = 0; j < 4; j++)
                        acc[i * 4 + j] = fmaf(av[i], bb[j], acc[i * 4 + j]);
            }
            __syncthreads();
        }
#pragma unroll
        for (int i = 0; i < 4; i++) {
            int row = ty * 4 + i;
            if (jt * 64 + row < cnt) {
                float w = sw[row];
                float4 bb = *(const float4*)&be[(size_t)e * NOUTD + ct * 64 + tx * 4];
                float4 o;
                o.x = w * fmaxf(acc[i * 4 + 0] + bb.x, 0.f);
                o.y = w * fmaxf(acc[i * 4 + 1] + bb.y, 0.f);
                o.z = w * fmaxf(acc[i * 4 + 2] + bb.z, 0.f);
                o.w = w * fmaxf(acc[i * 4 + 3] + bb.w, 0.f);
                float* op = &out[(size_t)stok[row] * NOUTD + ct * 64 + tx * 4];
                if (ACC) {
                    float4 p = *(const float4*)op;
                    o.x += p.x; o.y += p.y; o.z += p.z; o.w += p.w;
                }
                *(float4*)op = o;
            }
        }
        __syncthreads();
    }
}

extern "C" void kernel_launch(void* const* d_in, const int* in_sizes, int n_in,
                              void* d_out, int out_size, void* d_ws, size_t ws_size,
                              hipStream_t stream) {
    const float* x  = (const float*)d_in[0];
    const float* Wg = (const float*)d_in[1];
    const float* bg = (const float*)d_in[2];
    const float* We = (const float*)d_in[3];
    const float* be = (const float*)d_in[4];
    float* out = (float*)d_out;
    char* ws = (char*)d_ws;

    if (ws_size >= F_NEED) {
        _Float16* xf16 = (_Float16*)(ws + F_XF16);
        float* part    = (float*)(ws + F_PART);
        int*   counts  = (int*)(ws + F_CNT);
        int*   gtok    = (int*)(ws + F_GTOK);
        float* gw      = (float*)(ws + F_GW);

        k_prep<<<512, 256, 0, stream>>>(x, Wg, part, counts, xf16);
        k_top2_route<<<64, 256, 0, stream>>>(part, bg, counts, gtok, gw,
                                             out + (size_t)B_TOK * NOUTD);
        k_expert16<0><<<384, 512, 0, stream>>>(xf16, We, be, counts, gtok, gw, out, 0);
        k_expert16<1><<<384, 512, 0, stream>>>(xf16, We, be, counts, gtok, gw, out, 1);
    } else {
        float* logits = (float*)(ws + WS_LOGITS);
        int*   tkidx  = (int*)(ws + WS_TKIDX);
        float* tkw    = (float*)(ws + WS_TKW);
        int*   counts = (int*)(ws + WS_CTRS);
        int*   curs   = (int*)(ws + WS_CURS);
        int*   tilec  = (int*)(ws + WS_TILEC);
        int*   offsp  = (int*)(ws + WS_OFFS);
        int2*  tiles  = (int2*)(ws + WS_TILES);
        int*   gtok   = (int*)(ws + WS_GTOK);
        float* gw     = (float*)(ws + WS_GW);

        (void)hipMemsetAsync(ws + WS_CTRS, 0, 256, stream);
        k_gate<<<128, 256, 0, stream>>>(x, Wg, bg, logits);
        k_top2<<<32, 256, 0, stream>>>(logits, tkidx, tkw, counts);
        k_build<<<1, 64, 0, stream>>>(counts, offsp, curs, tiles, tilec,
                                      out + (size_t)B_TOK * NOUTD);
        k_scatter<<<32, 256, 0, stream>>>(tkidx, tkw, curs, gtok, gw);
        k_expert<0><<<1280, 256, 0, stream>>>(x, We, be, counts, offsp, tiles, tilec,
                                              gtok, gw, out, 0);
        k_expert<1><<<1280, 256, 0, stream>>>(x, We, be, counts, offsp, tiles, tilec,
                                              gtok, gw, out, 1);
    }
}

// Round 9
// 76.622 us; speedup vs baseline: 1.1101x; 1.1101x over previous
//
#include <hip/hip_runtime.h>
#include <hip/hip_bf16.h>
#include <hip/hip_fp16.h>
#include <cstdint>
#include <cstddef>

#define B_TOK 8192
#define NIN   512
#define NOUTD 512
#define NEXP  32

typedef _Float16 half8 __attribute__((ext_vector_type(8)));
typedef _Float16 half4 __attribute__((ext_vector_type(4)));
typedef float f32x4 __attribute__((ext_vector_type(4)));

// ---------------- fast-path workspace layout (bytes) ----------------
#define F_XF16  0u          // f16 [8192][512]        = 8 MB
#define F_WET   8388608u    // f16 [32][512][512]     = 16.8 MB (n-major: [e][n][k])
#define F_PART  25165824u   // f32 [4][8192][32]      = 4 MB (gate partials)
#define F_CNT   29360128u   // i32 [2][32]
#define F_GTOK  29360640u   // i32 [2][32][8192]      = 2 MB
#define F_GW    31457792u   // f32 [2][32][8192]      = 2 MB
#define F_NEED  33554944u

// ---------------- fallback (round-1) workspace layout ----------------
#define WS_LOGITS 0u
#define WS_TKIDX  (1u<<20)
#define WS_TKW    (WS_TKIDX + 65536u)
#define WS_CTRS   (WS_TKW + 65536u)
#define WS_CURS   (WS_CTRS + 256u)
#define WS_TILEC  (WS_CURS + 256u)
#define WS_OFFS   (WS_TILEC + 256u)
#define WS_TILES  (WS_OFFS + 256u)
#define WS_GTOK   (WS_TILES + 4096u)
#define WS_GW     (WS_GTOK + 65536u)

__device__ __forceinline__ void gload_lds16(const void* gsrc, void* ldst) {
    __builtin_amdgcn_global_load_lds((const __attribute__((address_space(1))) uint32_t*)gsrc,
                                     (__attribute__((address_space(3))) uint32_t*)ldst,
                                     16, 0, 0);
}

// ============ FAST K1: fused prep (round-7 proven) ============
// blocks [0,512): gate GEMM split-K=4 -> part[sl][tok][e]; writes xf16 for its
//                 own x slice; block 0 zeroes counts.
// blocks [512,2560): We [e][k][n] f32 -> WeT [e][n][k] f16 (LDS transpose).
__global__ __launch_bounds__(256) void k_prep(const float* __restrict__ x,
                                              const float* __restrict__ Wg,
                                              const float* __restrict__ We,
                                              float* __restrict__ part,
                                              int* __restrict__ counts,
                                              _Float16* __restrict__ xf16,
                                              _Float16* __restrict__ WeT) {
    __shared__ float xs[64 * 68];
    __shared__ float wgs[64 * 32];
    const int t = threadIdx.x;

    if (blockIdx.x >= 512) {
        const int cb = blockIdx.x - 512;
        const int e  = cb >> 6;
        const int kt = (cb >> 3) & 7, nt = cb & 7;
        const int k0 = kt * 64, n0 = nt * 64;
        const float* src = We + ((size_t)e * NIN + k0) * NOUTD + n0;
#pragma unroll
        for (int i = 0; i < 4; i++) {
            int idx = t + i * 256;           // 0..1023
            int k = idx >> 4, nq = idx & 15;
            float4 v = *(const float4*)&src[(size_t)k * NOUTD + nq * 4];
            *(float4*)&xs[k * 68 + nq * 4] = v;
        }
        __syncthreads();
        const int n = t >> 2, ks = (t & 3) * 16;
        half8 h0, h1;
#pragma unroll
        for (int j = 0; j < 8; j++) h0[j] = (_Float16)xs[(ks + j) * 68 + n];
#pragma unroll
        for (int j = 0; j < 8; j++) h1[j] = (_Float16)xs[(ks + 8 + j) * 68 + n];
        _Float16* dst = WeT + ((size_t)e * NOUTD + n0 + n) * NIN + k0 + ks;
        *(half8*)&dst[0] = h0;
        *(half8*)&dst[8] = h1;
        return;
    }

    if (blockIdx.x == 0 && t < 64) counts[t] = 0;
    const int tt = blockIdx.x >> 2, sl = blockIdx.x & 3;
    const int b0 = tt * 64;
    const int kbase = sl * 128;
    const int tok = t >> 2;
    const int eg  = (t & 3) * 8;

    float acc[8];
#pragma unroll
    for (int i = 0; i < 8; i++) acc[i] = 0.f;

    for (int ksi = 0; ksi < 2; ksi++) {
        const int k0 = kbase + ksi * 64;
#pragma unroll
        for (int i = 0; i < 4; i++) {
            int idx = t + i * 256;
            int tr = idx >> 4, kq = idx & 15;
            float4 v = *(const float4*)&x[(size_t)(b0 + tr) * NIN + k0 + kq * 4];
            *(float4*)&xs[tr * 68 + kq * 4] = v;
            half4 hv = {(_Float16)v.x, (_Float16)v.y, (_Float16)v.z, (_Float16)v.w};
            *(half4*)&xf16[(size_t)(b0 + tr) * NIN + k0 + kq * 4] = hv;
        }
#pragma unroll
        for (int i = 0; i < 2; i++) {
            int idx = t + i * 256;
            int r = idx >> 3, cq = idx & 7;
            float4 v = *(const float4*)&Wg[(size_t)(k0 + r) * NEXP + cq * 4];
            *(float4*)&wgs[r * 32 + cq * 4] = v;
        }
        __syncthreads();
#pragma unroll
        for (int kk = 0; kk < 64; kk++) {
            float a = xs[tok * 68 + kk];
            float4 b1 = *(const float4*)&wgs[kk * 32 + eg];
            float4 b2 = *(const float4*)&wgs[kk * 32 + eg + 4];
            acc[0] = fmaf(a, b1.x, acc[0]);
            acc[1] = fmaf(a, b1.y, acc[1]);
            acc[2] = fmaf(a, b1.z, acc[2]);
            acc[3] = fmaf(a, b1.w, acc[3]);
            acc[4] = fmaf(a, b2.x, acc[4]);
            acc[5] = fmaf(a, b2.y, acc[5]);
            acc[6] = fmaf(a, b2.z, acc[6]);
            acc[7] = fmaf(a, b2.w, acc[7]);
        }
        __syncthreads();
    }
    float4 o1 = {acc[0], acc[1], acc[2], acc[3]};
    float4 o2 = {acc[4], acc[5], acc[6], acc[7]};
    size_t ob = ((size_t)sl * B_TOK + b0 + tok) * NEXP + eg;
    *(float4*)&part[ob] = o1;
    *(float4*)&part[ob + 4] = o2;
}

// ============ FAST K2: sum partials + softmax + top2 + scatter + aux + zero(out) ============
// 64 blocks x 128 tokens; also zeroes the out buffer for the atomic expert kernel.
__global__ __launch_bounds__(256) void k_top2_route(const float* __restrict__ part,
                                                    const float* __restrict__ bg,
                                                    int* __restrict__ counts,
                                                    int* __restrict__ gtok,
                                                    float* __restrict__ gw,
                                                    float* __restrict__ out) {
    __shared__ float sacc[128 * 33];
    __shared__ int lc[64];
    __shared__ int lbase[64];
    const int t = threadIdx.x;
    const int b0 = blockIdx.x * 128;
    if (blockIdx.x == 0 && t == 0) out[(size_t)B_TOK * NOUTD] = 0.0f;  // aux

    for (int sl = 0; sl < 4; sl++) {
#pragma unroll
        for (int i = 0; i < 4; i++) {
            int idx = t + i * 256;            // 0..1023
            int tok = idx >> 3, ef = (idx & 7) * 4;
            float4 v = *(const float4*)&part[((size_t)sl * B_TOK + b0 + tok) * NEXP + ef];
            float* d = &sacc[tok * 33 + ef];
            if (sl == 0) { d[0] = v.x; d[1] = v.y; d[2] = v.z; d[3] = v.w; }
            else         { d[0] += v.x; d[1] += v.y; d[2] += v.z; d[3] += v.w; }
        }
    }
    if (t < 64) lc[t] = 0;
    __syncthreads();

    float w0 = 0.f, w1 = 0.f;
    int i0 = 0, i1 = 0;
    const bool act = t < 128;
    if (act) {
        float v[32];
#pragma unroll
        for (int e = 0; e < NEXP; e++) v[e] = sacc[t * 33 + e] + bg[e];
        float m = v[0];
#pragma unroll
        for (int e = 1; e < NEXP; e++) m = fmaxf(m, v[e]);
        float s = 0.f;
        float v0 = -3.0e38f, v1 = -3.0e38f;
#pragma unroll
        for (int e = 0; e < NEXP; e++) {
            float val = v[e];
            s += expf(val - m);
            if (val > v0) { v1 = v0; i1 = i0; v0 = val; i0 = e; }
            else if (val > v1) { v1 = val; i1 = e; }
        }
        float inv = 1.f / s;
        w0 = expf(v0 - m) * inv;
        w1 = expf(v1 - m) * inv;
    }
    int r0 = 0, r1 = 0;
    if (act) {
        r0 = atomicAdd(&lc[i0], 1);
        r1 = atomicAdd(&lc[32 + i1], 1);
    }
    __syncthreads();
    if (t < 64) lbase[t] = (lc[t] > 0) ? atomicAdd(&counts[t], lc[t]) : 0;
    __syncthreads();
    if (act) {
        int p0 = lbase[i0] + r0;
        int p1 = lbase[32 + i1] + r1;
        gtok[i0 * B_TOK + p0] = b0 + t;          gw[i0 * B_TOK + p0] = w0;
        gtok[(32 + i1) * B_TOK + p1] = b0 + t;   gw[(32 + i1) * B_TOK + p1] = w1;
    }

    // zero out[0 .. B_TOK*NOUTD): 64 blocks x 65536 floats each (float4 stores)
    {
        float4 z = {0.f, 0.f, 0.f, 0.f};
        float* obase = out + (size_t)blockIdx.x * 65536;
#pragma unroll
        for (int i = 0; i < 64; i++)
            *(float4*)&obase[i * 1024 + t * 4] = z;
    }
}

// ============ FAST K3: grouped expert GEMM, both rounds in ONE dispatch ============
// 512 threads, 8 waves (2x4), 128x128 tile, atomicAdd epilogue onto zeroed out.
__global__ __launch_bounds__(512) void k_expert16(const _Float16* __restrict__ xf16,
                                                  const _Float16* __restrict__ WeT,
                                                  const float* __restrict__ be,
                                                  const int* __restrict__ counts,
                                                  const int* __restrict__ gtok,
                                                  const float* __restrict__ gw,
                                                  float* __restrict__ out) {
    __shared__ _Float16 sA[2][128 * 32];   // [buf][token-row][k], 16B slots XOR-swizzled by row&3
    __shared__ _Float16 sB[2][128 * 32];
    __shared__ int   stok[128];
    __shared__ float sw[128];
    __shared__ float sbe[128];
    __shared__ int   pfx[65];

    const int t = threadIdx.x;
    const int lane = t & 63, wid = t >> 6;          // 8 waves
    const int wr = wid >> 2, wc = wid & 3;          // 2 x 4
    const int srow = t >> 2;                        // staging row 0..127
    const int ksw = (((t & 3) ^ (srow & 3)) * 8);   // swizzled k-offset (elements)
    const int g = lane >> 4, c16 = lane & 15;

    if (t == 0) {
        int a = 0;
#pragma unroll
        for (int s = 0; s < 64; s++) { pfx[s] = a; a += (counts[s] + 127) >> 7; }
        pfx[64] = a;
    }
    __syncthreads();
    const int ntiles = pfx[64] * 4;

    for (int tile = blockIdx.x; tile < ntiles; tile += gridDim.x) {
        const int rt = tile >> 2, ct = tile & 3, nb = ct * 128;
        int s = 0;
        while (pfx[s + 1] <= rt) s++;               // s = round*32 + e
        const int e = s & 31;
        const int jt = rt - pfx[s];
        const int cnt = counts[s];
        const int base = s * B_TOK + jt * 128;
        const int valid = min(128, cnt - jt * 128);

        if (t < 128) {
            int rr = min(t, valid - 1);
            stok[t] = gtok[base + rr];
            sw[t]   = gw[base + rr];
            sbe[t]  = be[e * NOUTD + nb + t];
        }
        __syncthreads();

        f32x4 acc[4][2];
#pragma unroll
        for (int m = 0; m < 4; m++)
#pragma unroll
            for (int n = 0; n < 2; n++) acc[m][n] = (f32x4){0.f, 0.f, 0.f, 0.f};

        const _Float16* WB = WeT + ((size_t)e * NOUTD + nb) * NIN;
        const int sbase = (wid * 16) * 32;   // wave-uniform LDS staging base

        gload_lds16(xf16 + (size_t)stok[srow] * NIN + ksw, &sA[0][sbase]);
        gload_lds16(WB + (size_t)srow * NIN + ksw,          &sB[0][sbase]);
        __syncthreads();

        int cur = 0;
        for (int k0 = 0; k0 < NIN; k0 += 32) {
            if (k0 + 32 < NIN) {
                gload_lds16(xf16 + (size_t)stok[srow] * NIN + k0 + 32 + ksw,
                            &sA[cur ^ 1][sbase]);
                gload_lds16(WB + (size_t)srow * NIN + k0 + 32 + ksw,
                            &sB[cur ^ 1][sbase]);
            }

            half8 fa[4], fb[2];
#pragma unroll
            for (int m = 0; m < 4; m++) {
                int ar = wr * 64 + m * 16 + c16;
                fa[m] = *(const half8*)&sA[cur][ar * 32 + ((g ^ (ar & 3)) * 8)];
            }
#pragma unroll
            for (int n = 0; n < 2; n++) {
                int br = wc * 32 + n * 16 + c16;
                fb[n] = *(const half8*)&sB[cur][br * 32 + ((g ^ (br & 3)) * 8)];
            }
#pragma unroll
            for (int m = 0; m < 4; m++)
#pragma unroll
                for (int n = 0; n < 2; n++)
                    acc[m][n] = __builtin_amdgcn_mfma_f32_16x16x32_f16(fa[m], fb[n], acc[m][n], 0, 0, 0);
            __syncthreads();
            cur ^= 1;
        }

        // epilogue: atomic accumulate (exactly 2 adds per out element across the
        // grid; float add commutes, so result is deterministic)
#pragma unroll
        for (int m = 0; m < 4; m++) {
#pragma unroll
            for (int q = 0; q < 4; q++) {
                int lr = wr * 64 + m * 16 + g * 4 + q;
                if (lr < valid) {
                    float w = sw[lr];
                    size_t ob = (size_t)stok[lr] * NOUTD + nb + wc * 32 + c16;
#pragma unroll
                    for (int n = 0; n < 2; n++) {
                        float v = fmaxf(acc[m][n][q] + sbe[wc * 32 + n * 16 + c16], 0.f) * w;
                        unsafeAtomicAdd(&out[ob + n * 16], v);
                    }
                }
            }
        }
        __syncthreads();
    }
}

// =====================================================================
// ==================== fallback (round-1, fp32) path ==================
// =====================================================================
__global__ __launch_bounds__(256) void k_gate(const float* __restrict__ x,
                                              const float* __restrict__ Wg,
                                              const float* __restrict__ bg,
                                              float* __restrict__ logits) {
    __shared__ float xs[64 * 68];
    __shared__ float wgs[64 * 32];
    const int t = threadIdx.x;
    const int b0 = blockIdx.x * 64;
    const int tok = t >> 2;
    const int eg  = (t & 3) * 8;
    float acc[8];
#pragma unroll
    for (int i = 0; i < 8; i++) acc[i] = 0.f;
    for (int k0 = 0; k0 < NIN; k0 += 64) {
#pragma unroll
        for (int i = 0; i < 4; i++) {
            int idx = t + i * 256;
            int tr = idx >> 4, kq = idx & 15;
            float4 v = *(const float4*)&x[(size_t)(b0 + tr) * NIN + k0 + kq * 4];
            *(float4*)&xs[tr * 68 + kq * 4] = v;
        }
#pragma unroll
        for (int i = 0; i < 2; i++) {
            int idx = t + i * 256;
            int r = idx >> 3, cq = idx & 7;
            float4 v = *(const float4*)&Wg[(size_t)(k0 + r) * NEXP + cq * 4];
            *(float4*)&wgs[r * 32 + cq * 4] = v;
        }
        __syncthreads();
#pragma unroll
        for (int kk = 0; kk < 64; kk++) {
            float a = xs[tok * 68 + kk];
            float4 b1 = *(const float4*)&wgs[kk * 32 + eg];
            float4 b2 = *(const float4*)&wgs[kk * 32 + eg + 4];
            acc[0] = fmaf(a, b1.x, acc[0]);
            acc[1] = fmaf(a, b1.y, acc[1]);
            acc[2] = fmaf(a, b1.z, acc[2]);
            acc[3] = fmaf(a, b1.w, acc[3]);
            acc[4] = fmaf(a, b2.x, acc[4]);
            acc[5] = fmaf(a, b2.y, acc[5]);
            acc[6] = fmaf(a, b2.z, acc[6]);
            acc[7] = fmaf(a, b2.w, acc[7]);
        }
        __syncthreads();
    }
    float4 o1, o2;
    o1.x = acc[0] + bg[eg + 0]; o1.y = acc[1] + bg[eg + 1];
    o1.z = acc[2] + bg[eg + 2]; o1.w = acc[3] + bg[eg + 3];
    o2.x = acc[4] + bg[eg + 4]; o2.y = acc[5] + bg[eg + 5];
    o2.z = acc[6] + bg[eg + 6]; o2.w = acc[7] + bg[eg + 7];
    size_t ob = (size_t)(b0 + tok) * NEXP + eg;
    *(float4*)&logits[ob] = o1;
    *(float4*)&logits[ob + 4] = o2;
}

__global__ __launch_bounds__(256) void k_top2(const float* __restrict__ logits,
                                              int* __restrict__ tkidx,
                                              float* __restrict__ tkw,
                                              int* __restrict__ counts) {
    __shared__ int lc[64];
    const int t = threadIdx.x;
    const int b = blockIdx.x * 256 + t;
    if (t < 64) lc[t] = 0;
    __syncthreads();
    float v[32];
#pragma unroll
    for (int i = 0; i < 8; i++) {
        float4 q = *(const float4*)&logits[(size_t)b * NEXP + i * 4];
        v[i * 4 + 0] = q.x; v[i * 4 + 1] = q.y; v[i * 4 + 2] = q.z; v[i * 4 + 3] = q.w;
    }
    float m = v[0];
#pragma unroll
    for (int e = 1; e < NEXP; e++) m = fmaxf(m, v[e]);
    float s = 0.f;
#pragma unroll
    for (int e = 0; e < NEXP; e++) s += expf(v[e] - m);
    float v0 = -3.0e38f, v1 = -3.0e38f;
    int i0 = 0, i1 = 0;
#pragma unroll
    for (int e = 0; e < NEXP; e++) {
        float val = v[e];
        if (val > v0) { v1 = v0; i1 = i0; v0 = val; i0 = e; }
        else if (val > v1) { v1 = val; i1 = e; }
    }
    float inv = 1.f / s;
    tkidx[b * 2 + 0] = i0; tkidx[b * 2 + 1] = i1;
    tkw[b * 2 + 0] = expf(v0 - m) * inv; tkw[b * 2 + 1] = expf(v1 - m) * inv;
    atomicAdd(&lc[i0], 1);
    atomicAdd(&lc[32 + i1], 1);
    __syncthreads();
    if (t < 64 && lc[t] > 0) atomicAdd(&counts[t], lc[t]);
}

__global__ __launch_bounds__(64) void k_build(const int* __restrict__ counts,
                                              int* __restrict__ offs,
                                              int* __restrict__ curs,
                                              int2* __restrict__ tiles,
                                              int* __restrict__ tilec,
                                              float* __restrict__ aux) {
    __shared__ int c[64];
    __shared__ int o[64];
    const int t = threadIdx.x;
    c[t] = counts[t];
    __syncthreads();
    if (t == 0) {
        int off = 0;
        for (int i = 0; i < 64; i++) {
            if ((i & 31) == 0) off = 0;
            o[i] = off;
            off += c[i];
        }
        aux[0] = 0.0f;
    }
    __syncthreads();
    offs[t] = o[t];
    curs[t] = o[t];
    if (t < 2) {
        int tc = 0;
        for (int e = 0; e < NEXP; e++) {
            int cnt = c[t * 32 + e];
            int nt = (cnt + 63) >> 6;
            for (int j = 0; j < nt; j++) tiles[t * 256 + tc++] = make_int2(e, j);
        }
        tilec[t] = tc;
    }
}

__global__ __launch_bounds__(256) void k_scatter(const int* __restrict__ tkidx,
                                                 const float* __restrict__ tkw,
                                                 int* __restrict__ curs,
                                                 int* __restrict__ gtok,
                                                 float* __restrict__ gw) {
    __shared__ int lc[64];
    __shared__ int lbase[64];
    const int t = threadIdx.x;
    const int b = blockIdx.x * 256 + t;
    if (t < 64) lc[t] = 0;
    __syncthreads();
    int i0 = tkidx[b * 2 + 0], i1 = tkidx[b * 2 + 1];
    int r0 = atomicAdd(&lc[i0], 1);
    int r1 = atomicAdd(&lc[32 + i1], 1);
    __syncthreads();
    if (t < 64) lbase[t] = (lc[t] > 0) ? atomicAdd(&curs[t], lc[t]) : 0;
    __syncthreads();
    int p0 = lbase[i0] + r0;
    int p1 = lbase[32 + i1] + r1;
    gtok[p0] = b;          gw[p0] = tkw[b * 2 + 0];
    gtok[8192 + p1] = b;   gw[8192 + p1] = tkw[b * 2 + 1];
}

template <int ACC>
__global__ __launch_bounds__(256) void k_expert(const float* __restrict__ x,
                                                const float* __restrict__ We,
                                                const float* __restrict__ be,
                                                const int* __restrict__ counts,
                                                const int* __restrict__ offs,
                                                const int2* __restrict__ tiles,
                                                const int* __restrict__ tilec,
                                                const int* __restrict__ gtok,
                                                const float* __restrict__ gw,
                                                float* __restrict__ out,
                                                int round) {
    __shared__ float xsT[32 * 68];
    __shared__ float wsd[32 * 64];
    __shared__ int   stok[64];
    __shared__ float sw[64];
    const int t = threadIdx.x;
    const int tx = t & 15, ty = t >> 4;
    const int ntiles = tilec[round] * 8;
    for (int tile = blockIdx.x; tile < ntiles; tile += gridDim.x) {
        int rt = tile >> 3, ct = tile & 7;
        int2 td = tiles[round * 256 + rt];
        int e = td.x, jt = td.y;
        int cnt = counts[round * 32 + e];
        int base = offs[round * 32 + e] + jt * 64;
        int valid = min(64, cnt - jt * 64);
        if (t < 64) {
            int rr = min(t, valid - 1);
            stok[t] = gtok[round * 8192 + base + rr];
            sw[t]   = gw  [round * 8192 + base + rr];
        }
        __syncthreads();
        float acc[16];
#pragma unroll
        for (int i = 0; i < 16; i++) acc[i] = 0.f;
        const float* Wb = We + (size_t)e * NIN * NOUTD + ct * 64;
        for (int k0 = 0; k0 < NIN; k0 += 32) {
#pragma unroll
            for (int i = 0; i < 2; i++) {
                int idx = t + i * 256;
                int tr = idx >> 3, kq = idx & 7;
                float4 v = *(const float4*)&x[(size_t)stok[tr] * NIN + k0 + kq * 4];
                xsT[(kq * 4 + 0) * 68 + tr] = v.x;
                xsT[(kq * 4 + 1) * 68 + tr] = v.y;
                xsT[(kq * 4 + 2) * 68 + tr] = v.z;
                xsT[(kq * 4 + 3) * 68 + tr] = v.w;
            }
#pragma unroll
            for (int i = 0; i < 2; i++) {
                int idx = t + i * 256;
                int r = idx >> 4, cq = idx & 15;
                *(float4*)&wsd[r * 64 + cq * 4] =
                    *(const float4*)&Wb[(size_t)(k0 + r) * NOUTD + cq * 4];
            }
            __syncthreads();
#pragma unroll
            for (int kk = 0; kk < 32; kk++) {
                float4 a  = *(const float4*)&xsT[kk * 68 + ty * 4];
                float4 bv = *(const float4*)&wsd[kk * 64 + tx * 4];
                float av[4] = {a.x, a.y, a.z, a.w};
                float bb[4] = {bv.x, bv.y, bv.z, bv.w};
#pragma unroll
                for (int i = 0; i < 4; i++)
#pragma unroll
                    for (int j = 0; j < 4; j++)
                        acc[i * 4 + j] = fmaf(av[i], bb[j], acc[i * 4 + j]);
            }
            __syncthreads();
        }
#pragma unroll
        for (int i = 0; i < 4; i++) {
            int row = ty * 4 + i;
            if (jt * 64 + row < cnt) {
                float w = sw[row];
                float4 bb = *(const float4*)&be[(size_t)e * NOUTD + ct * 64 + tx * 4];
                float4 o;
                o.x = w * fmaxf(acc[i * 4 + 0] + bb.x, 0.f);
                o.y = w * fmaxf(acc[i * 4 + 1] + bb.y, 0.f);
                o.z = w * fmaxf(acc[i * 4 + 2] + bb.z, 0.f);
                o.w = w * fmaxf(acc[i * 4 + 3] + bb.w, 0.f);
                float* op = &out[(size_t)stok[row] * NOUTD + ct * 64 + tx * 4];
                if (ACC) {
                    float4 p = *(const float4*)op;
                    o.x += p.x; o.y += p.y; o.z += p.z; o.w += p.w;
                }
                *(float4*)op = o;
            }
        }
        __syncthreads();
    }
}

extern "C" void kernel_launch(void* const* d_in, const int* in_sizes, int n_in,
                              void* d_out, int out_size, void* d_ws, size_t ws_size,
                              hipStream_t stream) {
    const float* x  = (const float*)d_in[0];
    const float* Wg = (const float*)d_in[1];
    const float* bg = (const float*)d_in[2];
    const float* We = (const float*)d_in[3];
    const float* be = (const float*)d_in[4];
    float* out = (float*)d_out;
    char* ws = (char*)d_ws;

    if (ws_size >= F_NEED) {
        _Float16* xf16 = (_Float16*)(ws + F_XF16);
        _Float16* WeT  = (_Float16*)(ws + F_WET);
        float* part    = (float*)(ws + F_PART);
        int*   counts  = (int*)(ws + F_CNT);
        int*   gtok    = (int*)(ws + F_GTOK);
        float* gw      = (float*)(ws + F_GW);

        k_prep<<<2560, 256, 0, stream>>>(x, Wg, We, part, counts, xf16, WeT);
        k_top2_route<<<64, 256, 0, stream>>>(part, bg, counts, gtok, gw, out);
        k_expert16<<<768, 512, 0, stream>>>(xf16, WeT, be, counts, gtok, gw, out);
    } else {
        float* logits = (float*)(ws + WS_LOGITS);
        int*   tkidx  = (int*)(ws + WS_TKIDX);
        float* tkw    = (float*)(ws + WS_TKW);
        int*   counts = (int*)(ws + WS_CTRS);
        int*   curs   = (int*)(ws + WS_CURS);
        int*   tilec  = (int*)(ws + WS_TILEC);
        int*   offsp  = (int*)(ws + WS_OFFS);
        int2*  tiles  = (int2*)(ws + WS_TILES);
        int*   gtok   = (int*)(ws + WS_GTOK);
        float* gw     = (float*)(ws + WS_GW);

        (void)hipMemsetAsync(ws + WS_CTRS, 0, 256, stream);
        k_gate<<<128, 256, 0, stream>>>(x, Wg, bg, logits);
        k_top2<<<32, 256, 0, stream>>>(logits, tkidx, tkw, counts);
        k_build<<<1, 64, 0, stream>>>(counts, offsp, curs, tiles, tilec,
                                      out + (size_t)B_TOK * NOUTD);
        k_scatter<<<32, 256, 0, stream>>>(tkidx, tkw, curs, gtok, gw);
        k_expert<0><<<1280, 256, 0, stream>>>(x, We, be, counts, offsp, tiles, tilec,
                                              gtok, gw, out, 0);
        k_expert<1><<<1280, 256, 0, stream>>>(x, We, be, counts, offsp, tiles, tilec,
                                              gtok, gw, out, 1);
    }
}

// Round 10
// 60.192 us; speedup vs baseline: 1.4131x; 1.2730x over previous
//
#include <hip/hip_runtime.h>
#include <hip/hip_bf16.h>
#include <hip/hip_fp16.h>
#include <cstdint>
#include <cstddef>

#define B_TOK 8192
#define NIN   512
#define NOUTD 512
#define NEXP  32

typedef _Float16 half8 __attribute__((ext_vector_type(8)));
typedef _Float16 half4 __attribute__((ext_vector_type(4)));
typedef float f32x4 __attribute__((ext_vector_type(4)));

// ---------------- fast-path workspace layout (bytes) ----------------
#define F_XF16  0u          // f16 [8192][512]        = 8 MB
#define F_WET   8388608u    // f16 [32][512][512]     = 16.8 MB (n-major: [e][n][k])
#define F_PART  25165824u   // f32 [4][8192][32]      = 4 MB (gate partials)
#define F_CNT   29360128u   // i32 [2][32]
#define F_GTOK  29360640u   // i32 [2][32][8192]      = 2 MB
#define F_GW    31457792u   // f32 [2][32][8192]      = 2 MB
#define F_NEED  33554944u

// ---------------- fallback (round-1) workspace layout ----------------
#define WS_LOGITS 0u
#define WS_TKIDX  (1u<<20)
#define WS_TKW    (WS_TKIDX + 65536u)
#define WS_CTRS   (WS_TKW + 65536u)
#define WS_CURS   (WS_CTRS + 256u)
#define WS_TILEC  (WS_CURS + 256u)
#define WS_OFFS   (WS_TILEC + 256u)
#define WS_TILES  (WS_OFFS + 256u)
#define WS_GTOK   (WS_TILES + 4096u)
#define WS_GW     (WS_GTOK + 65536u)

__device__ __forceinline__ void gload_lds16(const void* gsrc, void* ldst) {
    __builtin_amdgcn_global_load_lds((const __attribute__((address_space(1))) uint32_t*)gsrc,
                                     (__attribute__((address_space(3))) uint32_t*)ldst,
                                     16, 0, 0);
}

// ============ FAST K1: fused prep (round-7 proven) ============
// blocks [0,512): gate GEMM split-K=4 -> part[sl][tok][e]; writes xf16 for its
//                 own x slice; block 0 zeroes counts.
// blocks [512,2560): We [e][k][n] f32 -> WeT [e][n][k] f16 (LDS transpose).
__global__ __launch_bounds__(256) void k_prep(const float* __restrict__ x,
                                              const float* __restrict__ Wg,
                                              const float* __restrict__ We,
                                              float* __restrict__ part,
                                              int* __restrict__ counts,
                                              _Float16* __restrict__ xf16,
                                              _Float16* __restrict__ WeT) {
    __shared__ float xs[64 * 68];
    __shared__ float wgs[64 * 32];
    const int t = threadIdx.x;

    if (blockIdx.x >= 512) {
        const int cb = blockIdx.x - 512;
        const int e  = cb >> 6;
        const int kt = (cb >> 3) & 7, nt = cb & 7;
        const int k0 = kt * 64, n0 = nt * 64;
        const float* src = We + ((size_t)e * NIN + k0) * NOUTD + n0;
#pragma unroll
        for (int i = 0; i < 4; i++) {
            int idx = t + i * 256;           // 0..1023
            int k = idx >> 4, nq = idx & 15;
            float4 v = *(const float4*)&src[(size_t)k * NOUTD + nq * 4];
            *(float4*)&xs[k * 68 + nq * 4] = v;
        }
        __syncthreads();
        const int n = t >> 2, ks = (t & 3) * 16;
        half8 h0, h1;
#pragma unroll
        for (int j = 0; j < 8; j++) h0[j] = (_Float16)xs[(ks + j) * 68 + n];
#pragma unroll
        for (int j = 0; j < 8; j++) h1[j] = (_Float16)xs[(ks + 8 + j) * 68 + n];
        _Float16* dst = WeT + ((size_t)e * NOUTD + n0 + n) * NIN + k0 + ks;
        *(half8*)&dst[0] = h0;
        *(half8*)&dst[8] = h1;
        return;
    }

    if (blockIdx.x == 0 && t < 64) counts[t] = 0;
    const int tt = blockIdx.x >> 2, sl = blockIdx.x & 3;
    const int b0 = tt * 64;
    const int kbase = sl * 128;
    const int tok = t >> 2;
    const int eg  = (t & 3) * 8;

    float acc[8];
#pragma unroll
    for (int i = 0; i < 8; i++) acc[i] = 0.f;

    for (int ksi = 0; ksi < 2; ksi++) {
        const int k0 = kbase + ksi * 64;
#pragma unroll
        for (int i = 0; i < 4; i++) {
            int idx = t + i * 256;
            int tr = idx >> 4, kq = idx & 15;
            float4 v = *(const float4*)&x[(size_t)(b0 + tr) * NIN + k0 + kq * 4];
            *(float4*)&xs[tr * 68 + kq * 4] = v;
            half4 hv = {(_Float16)v.x, (_Float16)v.y, (_Float16)v.z, (_Float16)v.w};
            *(half4*)&xf16[(size_t)(b0 + tr) * NIN + k0 + kq * 4] = hv;
        }
#pragma unroll
        for (int i = 0; i < 2; i++) {
            int idx = t + i * 256;
            int r = idx >> 3, cq = idx & 7;
            float4 v = *(const float4*)&Wg[(size_t)(k0 + r) * NEXP + cq * 4];
            *(float4*)&wgs[r * 32 + cq * 4] = v;
        }
        __syncthreads();
#pragma unroll
        for (int kk = 0; kk < 64; kk++) {
            float a = xs[tok * 68 + kk];
            float4 b1 = *(const float4*)&wgs[kk * 32 + eg];
            float4 b2 = *(const float4*)&wgs[kk * 32 + eg + 4];
            acc[0] = fmaf(a, b1.x, acc[0]);
            acc[1] = fmaf(a, b1.y, acc[1]);
            acc[2] = fmaf(a, b1.z, acc[2]);
            acc[3] = fmaf(a, b1.w, acc[3]);
            acc[4] = fmaf(a, b2.x, acc[4]);
            acc[5] = fmaf(a, b2.y, acc[5]);
            acc[6] = fmaf(a, b2.z, acc[6]);
            acc[7] = fmaf(a, b2.w, acc[7]);
        }
        __syncthreads();
    }
    float4 o1 = {acc[0], acc[1], acc[2], acc[3]};
    float4 o2 = {acc[4], acc[5], acc[6], acc[7]};
    size_t ob = ((size_t)sl * B_TOK + b0 + tok) * NEXP + eg;
    *(float4*)&part[ob] = o1;
    *(float4*)&part[ob + 4] = o2;
}

// ============ FAST K2: sum partials + softmax + top2 + scatter + aux ============
// 64 blocks x 128 tokens
__global__ __launch_bounds__(256) void k_top2_route(const float* __restrict__ part,
                                                    const float* __restrict__ bg,
                                                    int* __restrict__ counts,
                                                    int* __restrict__ gtok,
                                                    float* __restrict__ gw,
                                                    float* __restrict__ aux) {
    __shared__ float sacc[128 * 33];
    __shared__ int lc[64];
    __shared__ int lbase[64];
    const int t = threadIdx.x;
    const int b0 = blockIdx.x * 128;
    if (blockIdx.x == 0 && t == 0) aux[0] = 0.0f;

    for (int sl = 0; sl < 4; sl++) {
#pragma unroll
        for (int i = 0; i < 4; i++) {
            int idx = t + i * 256;            // 0..1023
            int tok = idx >> 3, ef = (idx & 7) * 4;
            float4 v = *(const float4*)&part[((size_t)sl * B_TOK + b0 + tok) * NEXP + ef];
            float* d = &sacc[tok * 33 + ef];
            if (sl == 0) { d[0] = v.x; d[1] = v.y; d[2] = v.z; d[3] = v.w; }
            else         { d[0] += v.x; d[1] += v.y; d[2] += v.z; d[3] += v.w; }
        }
    }
    if (t < 64) lc[t] = 0;
    __syncthreads();

    float w0 = 0.f, w1 = 0.f;
    int i0 = 0, i1 = 0;
    const bool act = t < 128;
    if (act) {
        float v[32];
#pragma unroll
        for (int e = 0; e < NEXP; e++) v[e] = sacc[t * 33 + e] + bg[e];
        float m = v[0];
#pragma unroll
        for (int e = 1; e < NEXP; e++) m = fmaxf(m, v[e]);
        float s = 0.f;
        float v0 = -3.0e38f, v1 = -3.0e38f;
#pragma unroll
        for (int e = 0; e < NEXP; e++) {
            float val = v[e];
            s += expf(val - m);
            if (val > v0) { v1 = v0; i1 = i0; v0 = val; i0 = e; }
            else if (val > v1) { v1 = val; i1 = e; }
        }
        float inv = 1.f / s;
        w0 = expf(v0 - m) * inv;
        w1 = expf(v1 - m) * inv;
    }
    int r0 = 0, r1 = 0;
    if (act) {
        r0 = atomicAdd(&lc[i0], 1);
        r1 = atomicAdd(&lc[32 + i1], 1);
    }
    __syncthreads();
    if (t < 64) lbase[t] = (lc[t] > 0) ? atomicAdd(&counts[t], lc[t]) : 0;
    __syncthreads();
    if (act) {
        int p0 = lbase[i0] + r0;
        int p1 = lbase[32 + i1] + r1;
        gtok[i0 * B_TOK + p0] = b0 + t;          gw[i0 * B_TOK + p0] = w0;
        gtok[(32 + i1) * B_TOK + p1] = b0 + t;   gw[(32 + i1) * B_TOK + p1] = w1;
    }
}

// ============ FAST K3/K4: grouped expert GEMM, MFMA f16, 128x128, BK=64 ============
// 512 threads, 8 waves (2x4); each wave computes 64 tok x 32 n.
// LDS rows are 64 f16 (128B = 8 x 16B slots), XOR-swizzled: slot' = slot ^ (row&7).
// One tile per block; bijective XCD-chunked tile mapping for L2 A-panel reuse.
template <int ACC>
__global__ __launch_bounds__(512) void k_expert16(const _Float16* __restrict__ xf16,
                                                  const _Float16* __restrict__ WeT,
                                                  const float* __restrict__ be,
                                                  const int* __restrict__ counts,
                                                  const int* __restrict__ gtok,
                                                  const float* __restrict__ gw,
                                                  float* __restrict__ out,
                                                  int round) {
    __shared__ _Float16 sA[2][128 * 64];   // 16 KB per buf
    __shared__ _Float16 sB[2][128 * 64];
    __shared__ int   stok[128];
    __shared__ float sw[128];
    __shared__ float sbe[128];
    __shared__ int   pfx[33];

    const int t = threadIdx.x;
    const int lane = t & 63, wid = t >> 6;          // 8 waves
    const int wr = wid >> 2, wc = wid & 3;          // 2 x 4
    const int g = lane >> 4, c16 = lane & 15;

    if (t == 0) {
        int a = 0;
#pragma unroll
        for (int e = 0; e < NEXP; e++) { pfx[e] = a; a += (counts[round * 32 + e] + 127) >> 7; }
        pfx[32] = a;
    }
    __syncthreads();
    const int ntiles = pfx[32] * 4;

    // bijective XCD-chunked mapping (m204): contiguous tile ranges per XCD so the
    // 4 consecutive tiles sharing an A-panel land on one XCD's L2.
    {
        const int xcd = blockIdx.x & 7, pos = blockIdx.x >> 3;
        const int q = ntiles >> 3, r = ntiles & 7;
        const int cterr = q + (xcd < r ? 1 : 0);
        if (pos >= cterr) return;
        const int start = (xcd < r) ? xcd * (q + 1) : r * (q + 1) + (xcd - r) * q;
        const int tile = start + pos;

        const int rt = tile >> 2, ct = tile & 3, nb = ct * 128;
        int e = 0;
        while (pfx[e + 1] <= rt) e++;
        const int jt = rt - pfx[e];
        const int cnt = counts[round * 32 + e];
        const int base = (round * 32 + e) * B_TOK + jt * 128;
        const int valid = min(128, cnt - jt * 128);

        if (t < 128) {
            int rr = min(t, valid - 1);
            stok[t] = gtok[base + rr];
            sw[t]   = gw[base + rr];
            sbe[t]  = be[e * NOUTD + nb + t];
        }
        __syncthreads();

        f32x4 acc[4][2];
#pragma unroll
        for (int m = 0; m < 4; m++)
#pragma unroll
            for (int n = 0; n < 2; n++) acc[m][n] = (f32x4){0.f, 0.f, 0.f, 0.f};

        const _Float16* WB = WeT + ((size_t)e * NOUTD + nb) * NIN;

        // staging geometry: per matrix, 2 row-blocks of 8 rows per wave.
        // rb = wid*2+i; row = rb*8 + (lane>>3); dest slot sd = lane&7;
        // source k-slot ss = sd ^ (row&7)  (involution; read undoes it).
        const int r0a = wid * 16 + (lane >> 3);          // row for i=0 (rb=wid*2)
        const int r1a = r0a + 8;                         // row for i=1
        const int ss0 = (lane & 7) ^ (r0a & 7);
        const int ss1 = (lane & 7) ^ (r1a & 7);

#define STAGE_AB(buf, kofs)                                                        \
        gload_lds16(xf16 + (size_t)stok[r0a] * NIN + (kofs) + ss0 * 8,             \
                    &sA[buf][(wid * 16) * 64]);                                    \
        gload_lds16(xf16 + (size_t)stok[r1a] * NIN + (kofs) + ss1 * 8,             \
                    &sA[buf][(wid * 16 + 8) * 64]);                                \
        gload_lds16(WB + (size_t)r0a * NIN + (kofs) + ss0 * 8,                     \
                    &sB[buf][(wid * 16) * 64]);                                    \
        gload_lds16(WB + (size_t)r1a * NIN + (kofs) + ss1 * 8,                     \
                    &sB[buf][(wid * 16 + 8) * 64]);

        STAGE_AB(0, 0)
        __syncthreads();

        int cur = 0;
        for (int k0 = 0; k0 < NIN; k0 += 64) {
            if (k0 + 64 < NIN) {
                if (cur == 0) { STAGE_AB(1, k0 + 64) }
                else          { STAGE_AB(0, k0 + 64) }
            }

            half8 fa[2][4], fb[2][2];
#pragma unroll
            for (int ks = 0; ks < 2; ks++) {
#pragma unroll
                for (int m = 0; m < 4; m++) {
                    int ar = wr * 64 + m * 16 + c16;
                    fa[ks][m] = *(const half8*)&sA[cur][ar * 64 + (((ks * 4 + g) ^ (ar & 7)) * 8)];
                }
#pragma unroll
                for (int n = 0; n < 2; n++) {
                    int br = wc * 32 + n * 16 + c16;
                    fb[ks][n] = *(const half8*)&sB[cur][br * 64 + (((ks * 4 + g) ^ (br & 7)) * 8)];
                }
            }
#pragma unroll
            for (int ks = 0; ks < 2; ks++)
#pragma unroll
                for (int m = 0; m < 4; m++)
#pragma unroll
                    for (int n = 0; n < 2; n++)
                        acc[m][n] = __builtin_amdgcn_mfma_f32_16x16x32_f16(fa[ks][m], fb[ks][n], acc[m][n], 0, 0, 0);
            __syncthreads();
            cur ^= 1;
        }
#undef STAGE_AB

#pragma unroll
        for (int m = 0; m < 4; m++) {
#pragma unroll
            for (int q2 = 0; q2 < 4; q2++) {
                int lr = wr * 64 + m * 16 + g * 4 + q2;
                if (lr < valid) {
                    float w = sw[lr];
                    size_t ob = (size_t)stok[lr] * NOUTD + nb + wc * 32 + c16;
#pragma unroll
                    for (int n = 0; n < 2; n++) {
                        float v = fmaxf(acc[m][n][q2] + sbe[wc * 32 + n * 16 + c16], 0.f) * w;
                        float* op = &out[ob + n * 16];
                        if (ACC) v += *op;
                        *op = v;
                    }
                }
            }
        }
    }
}

// =====================================================================
// ==================== fallback (round-1, fp32) path ==================
// =====================================================================
__global__ __launch_bounds__(256) void k_gate(const float* __restrict__ x,
                                              const float* __restrict__ Wg,
                                              const float* __restrict__ bg,
                                              float* __restrict__ logits) {
    __shared__ float xs[64 * 68];
    __shared__ float wgs[64 * 32];
    const int t = threadIdx.x;
    const int b0 = blockIdx.x * 64;
    const int tok = t >> 2;
    const int eg  = (t & 3) * 8;
    float acc[8];
#pragma unroll
    for (int i = 0; i < 8; i++) acc[i] = 0.f;
    for (int k0 = 0; k0 < NIN; k0 += 64) {
#pragma unroll
        for (int i = 0; i < 4; i++) {
            int idx = t + i * 256;
            int tr = idx >> 4, kq = idx & 15;
            float4 v = *(const float4*)&x[(size_t)(b0 + tr) * NIN + k0 + kq * 4];
            *(float4*)&xs[tr * 68 + kq * 4] = v;
        }
#pragma unroll
        for (int i = 0; i < 2; i++) {
            int idx = t + i * 256;
            int r = idx >> 3, cq = idx & 7;
            float4 v = *(const float4*)&Wg[(size_t)(k0 + r) * NEXP + cq * 4];
            *(float4*)&wgs[r * 32 + cq * 4] = v;
        }
        __syncthreads();
#pragma unroll
        for (int kk = 0; kk < 64; kk++) {
            float a = xs[tok * 68 + kk];
            float4 b1 = *(const float4*)&wgs[kk * 32 + eg];
            float4 b2 = *(const float4*)&wgs[kk * 32 + eg + 4];
            acc[0] = fmaf(a, b1.x, acc[0]);
            acc[1] = fmaf(a, b1.y, acc[1]);
            acc[2] = fmaf(a, b1.z, acc[2]);
            acc[3] = fmaf(a, b1.w, acc[3]);
            acc[4] = fmaf(a, b2.x, acc[4]);
            acc[5] = fmaf(a, b2.y, acc[5]);
            acc[6] = fmaf(a, b2.z, acc[6]);
            acc[7] = fmaf(a, b2.w, acc[7]);
        }
        __syncthreads();
    }
    float4 o1, o2;
    o1.x = acc[0] + bg[eg + 0]; o1.y = acc[1] + bg[eg + 1];
    o1.z = acc[2] + bg[eg + 2]; o1.w = acc[3] + bg[eg + 3];
    o2.x = acc[4] + bg[eg + 4]; o2.y = acc[5] + bg[eg + 5];
    o2.z = acc[6] + bg[eg + 6]; o2.w = acc[7] + bg[eg + 7];
    size_t ob = (size_t)(b0 + tok) * NEXP + eg;
    *(float4*)&logits[ob] = o1;
    *(float4*)&logits[ob + 4] = o2;
}

__global__ __launch_bounds__(256) void k_top2(const float* __restrict__ logits,
                                              int* __restrict__ tkidx,
                                              float* __restrict__ tkw,
                                              int* __restrict__ counts) {
    __shared__ int lc[64];
    const int t = threadIdx.x;
    const int b = blockIdx.x * 256 + t;
    if (t < 64) lc[t] = 0;
    __syncthreads();
    float v[32];
#pragma unroll
    for (int i = 0; i < 8; i++) {
        float4 q = *(const float4*)&logits[(size_t)b * NEXP + i * 4];
        v[i * 4 + 0] = q.x; v[i * 4 + 1] = q.y; v[i * 4 + 2] = q.z; v[i * 4 + 3] = q.w;
    }
    float m = v[0];
#pragma unroll
    for (int e = 1; e < NEXP; e++) m = fmaxf(m, v[e]);
    float s = 0.f;
#pragma unroll
    for (int e = 0; e < NEXP; e++) s += expf(v[e] - m);
    float v0 = -3.0e38f, v1 = -3.0e38f;
    int i0 = 0, i1 = 0;
#pragma unroll
    for (int e = 0; e < NEXP; e++) {
        float val = v[e];
        if (val > v0) { v1 = v0; i1 = i0; v0 = val; i0 = e; }
        else if (val > v1) { v1 = val; i1 = e; }
    }
    float inv = 1.f / s;
    tkidx[b * 2 + 0] = i0; tkidx[b * 2 + 1] = i1;
    tkw[b * 2 + 0] = expf(v0 - m) * inv; tkw[b * 2 + 1] = expf(v1 - m) * inv;
    atomicAdd(&lc[i0], 1);
    atomicAdd(&lc[32 + i1], 1);
    __syncthreads();
    if (t < 64 && lc[t] > 0) atomicAdd(&counts[t], lc[t]);
}

__global__ __launch_bounds__(64) void k_build(const int* __restrict__ counts,
                                              int* __restrict__ offs,
                                              int* __restrict__ curs,
                                              int2* __restrict__ tiles,
                                              int* __restrict__ tilec,
                                              float* __restrict__ aux) {
    __shared__ int c[64];
    __shared__ int o[64];
    const int t = threadIdx.x;
    c[t] = counts[t];
    __syncthreads();
    if (t == 0) {
        int off = 0;
        for (int i = 0; i < 64; i++) {
            if ((i & 31) == 0) off = 0;
            o[i] = off;
            off += c[i];
        }
        aux[0] = 0.0f;
    }
    __syncthreads();
    offs[t] = o[t];
    curs[t] = o[t];
    if (t < 2) {
        int tc = 0;
        for (int e = 0; e < NEXP; e++) {
            int cnt = c[t * 32 + e];
            int nt = (cnt + 63) >> 6;
            for (int j = 0; j < nt; j++) tiles[t * 256 + tc++] = make_int2(e, j);
        }
        tilec[t] = tc;
    }
}

__global__ __launch_bounds__(256) void k_scatter(const int* __restrict__ tkidx,
                                                 const float* __restrict__ tkw,
                                                 int* __restrict__ curs,
                                                 int* __restrict__ gtok,
                                                 float* __restrict__ gw) {
    __shared__ int lc[64];
    __shared__ int lbase[64];
    const int t = threadIdx.x;
    const int b = blockIdx.x * 256 + t;
    if (t < 64) lc[t] = 0;
    __syncthreads();
    int i0 = tkidx[b * 2 + 0], i1 = tkidx[b * 2 + 1];
    int r0 = atomicAdd(&lc[i0], 1);
    int r1 = atomicAdd(&lc[32 + i1], 1);
    __syncthreads();
    if (t < 64) lbase[t] = (lc[t] > 0) ? atomicAdd(&curs[t], lc[t]) : 0;
    __syncthreads();
    int p0 = lbase[i0] + r0;
    int p1 = lbase[32 + i1] + r1;
    gtok[p0] = b;          gw[p0] = tkw[b * 2 + 0];
    gtok[8192 + p1] = b;   gw[8192 + p1] = tkw[b * 2 + 1];
}

template <int ACC>
__global__ __launch_bounds__(256) void k_expert(const float* __restrict__ x,
                                                const float* __restrict__ We,
                                                const float* __restrict__ be,
                                                const int* __restrict__ counts,
                                                const int* __restrict__ offs,
                                                const int2* __restrict__ tiles,
                                                const int* __restrict__ tilec,
                                                const int* __restrict__ gtok,
                                                const float* __restrict__ gw,
                                                float* __restrict__ out,
                                                int round) {
    __shared__ float xsT[32 * 68];
    __shared__ float wsd[32 * 64];
    __shared__ int   stok[64];
    __shared__ float sw[64];
    const int t = threadIdx.x;
    const int tx = t & 15, ty = t >> 4;
    const int ntiles = tilec[round] * 8;
    for (int tile = blockIdx.x; tile < ntiles; tile += gridDim.x) {
        int rt = tile >> 3, ct = tile & 7;
        int2 td = tiles[round * 256 + rt];
        int e = td.x, jt = td.y;
        int cnt = counts[round * 32 + e];
        int base = offs[round * 32 + e] + jt * 64;
        int valid = min(64, cnt - jt * 64);
        if (t < 64) {
            int rr = min(t, valid - 1);
            stok[t] = gtok[round * 8192 + base + rr];
            sw[t]   = gw  [round * 8192 + base + rr];
        }
        __syncthreads();
        float acc[16];
#pragma unroll
        for (int i = 0; i < 16; i++) acc[i] = 0.f;
        const float* Wb = We + (size_t)e * NIN * NOUTD + ct * 64;
        for (int k0 = 0; k0 < NIN; k0 += 32) {
#pragma unroll
            for (int i = 0; i < 2; i++) {
                int idx = t + i * 256;
                int tr = idx >> 3, kq = idx & 7;
                float4 v = *(const float4*)&x[(size_t)stok[tr] * NIN + k0 + kq * 4];
                xsT[(kq * 4 + 0) * 68 + tr] = v.x;
                xsT[(kq * 4 + 1) * 68 + tr] = v.y;
                xsT[(kq * 4 + 2) * 68 + tr] = v.z;
                xsT[(kq * 4 + 3) * 68 + tr] = v.w;
            }
#pragma unroll
            for (int i = 0; i < 2; i++) {
                int idx = t + i * 256;
                int r = idx >> 4, cq = idx & 15;
                *(float4*)&wsd[r * 64 + cq * 4] =
                    *(const float4*)&Wb[(size_t)(k0 + r) * NOUTD + cq * 4];
            }
            __syncthreads();
#pragma unroll
            for (int kk = 0; kk < 32; kk++) {
                float4 a  = *(const float4*)&xsT[kk * 68 + ty * 4];
                float4 bv = *(const float4*)&wsd[kk * 64 + tx * 4];
                float av[4] = {a.x, a.y, a.z, a.w};
                float bb[4] = {bv.x, bv.y, bv.z, bv.w};
#pragma unroll
                for (int i = 0; i < 4; i++)
#pragma unroll
                    for (int j = 0; j < 4; j++)
                        acc[i * 4 + j] = fmaf(av[i], bb[j], acc[i * 4 + j]);
            }
            __syncthreads();
        }
#pragma unroll
        for (int i = 0; i < 4; i++) {
            int row = ty * 4 + i;
            if (jt * 64 + row < cnt) {
                float w = sw[row];
                float4 bb = *(const float4*)&be[(size_t)e * NOUTD + ct * 64 + tx * 4];
                float4 o;
                o.x = w * fmaxf(acc[i * 4 + 0] + bb.x, 0.f);
                o.y = w * fmaxf(acc[i * 4 + 1] + bb.y, 0.f);
                o.z = w * fmaxf(acc[i * 4 + 2] + bb.z, 0.f);
                o.w = w * fmaxf(acc[i * 4 + 3] + bb.w, 0.f);
                float* op = &out[(size_t)stok[row] * NOUTD + ct * 64 + tx * 4];
                if (ACC) {
                    float4 p = *(const float4*)op;
                    o.x += p.x; o.y += p.y; o.z += p.z; o.w += p.w;
                }
                *(float4*)op = o;
            }
        }
        __syncthreads();
    }
}

extern "C" void kernel_launch(void* const* d_in, const int* in_sizes, int n_in,
                              void* d_out, int out_size, void* d_ws, size_t ws_size,
                              hipStream_t stream) {
    const float* x  = (const float*)d_in[0];
    const float* Wg = (const float*)d_in[1];
    const float* bg = (const float*)d_in[2];
    const float* We = (const float*)d_in[3];
    const float* be = (const float*)d_in[4];
    float* out = (float*)d_out;
    char* ws = (char*)d_ws;

    if (ws_size >= F_NEED) {
        _Float16* xf16 = (_Float16*)(ws + F_XF16);
        _Float16* WeT  = (_Float16*)(ws + F_WET);
        float* part    = (float*)(ws + F_PART);
        int*   counts  = (int*)(ws + F_CNT);
        int*   gtok    = (int*)(ws + F_GTOK);
        float* gw      = (float*)(ws + F_GW);

        k_prep<<<2560, 256, 0, stream>>>(x, Wg, We, part, counts, xf16, WeT);
        k_top2_route<<<64, 256, 0, stream>>>(part, bg, counts, gtok, gw,
                                             out + (size_t)B_TOK * NOUTD);
        k_expert16<0><<<384, 512, 0, stream>>>(xf16, WeT, be, counts, gtok, gw, out, 0);
        k_expert16<1><<<384, 512, 0, stream>>>(xf16, WeT, be, counts, gtok, gw, out, 1);
    } else {
        float* logits = (float*)(ws + WS_LOGITS);
        int*   tkidx  = (int*)(ws + WS_TKIDX);
        float* tkw    = (float*)(ws + WS_TKW);
        int*   counts = (int*)(ws + WS_CTRS);
        int*   curs   = (int*)(ws + WS_CURS);
        int*   tilec  = (int*)(ws + WS_TILEC);
        int*   offsp  = (int*)(ws + WS_OFFS);
        int2*  tiles  = (int2*)(ws + WS_TILES);
        int*   gtok   = (int*)(ws + WS_GTOK);
        float* gw     = (float*)(ws + WS_GW);

        (void)hipMemsetAsync(ws + WS_CTRS, 0, 256, stream);
        k_gate<<<128, 256, 0, stream>>>(x, Wg, bg, logits);
        k_top2<<<32, 256, 0, stream>>>(logits, tkidx, tkw, counts);
        k_build<<<1, 64, 0, stream>>>(counts, offsp, curs, tiles, tilec,
                                      out + (size_t)B_TOK * NOUTD);
        k_scatter<<<32, 256, 0, stream>>>(tkidx, tkw, curs, gtok, gw);
        k_expert<0><<<1280, 256, 0, stream>>>(x, We, be, counts, offsp, tiles, tilec,
                                              gtok, gw, out, 0);
        k_expert<1><<<1280, 256, 0, stream>>>(x, We, be, counts, offsp, tiles, tilec,
                                              gtok, gw, out, 1);
    }
}

// Round 11
// 55.646 us; speedup vs baseline: 1.5286x; 1.0817x over previous
//
#include <hip/hip_runtime.h>
#include <hip/hip_bf16.h>
#include <hip/hip_fp16.h>
#include <cstdint>
#include <cstddef>

#define B_TOK 8192
#define NIN   512
#define NOUTD 512
#define NEXP  32

typedef _Float16 half8 __attribute__((ext_vector_type(8)));
typedef _Float16 half4 __attribute__((ext_vector_type(4)));
typedef float f32x4 __attribute__((ext_vector_type(4)));

// ---------------- fast-path workspace layout (bytes) ----------------
#define F_XF16  0u          // f16 [8192][512]        = 8 MB
#define F_WET   8388608u    // f16 [32][512][512]     = 16.8 MB (n-major: [e][n][k])
#define F_PART  25165824u   // f32 [4][8192][32]      = 4 MB (gate partials)
#define F_CNT   29360128u   // i32 [2][32]
#define F_GTOK  29360640u   // i32 [2][32][8192]      = 2 MB
#define F_GW    31457792u   // f32 [2][32][8192]      = 2 MB
#define F_NEED  33554944u

// ---------------- fallback (round-1) workspace layout ----------------
#define WS_LOGITS 0u
#define WS_TKIDX  (1u<<20)
#define WS_TKW    (WS_TKIDX + 65536u)
#define WS_CTRS   (WS_TKW + 65536u)
#define WS_CURS   (WS_CTRS + 256u)
#define WS_TILEC  (WS_CURS + 256u)
#define WS_OFFS   (WS_TILEC + 256u)
#define WS_TILES  (WS_OFFS + 256u)
#define WS_GTOK   (WS_TILES + 4096u)
#define WS_GW     (WS_GTOK + 65536u)

__device__ __forceinline__ void gload_lds16(const void* gsrc, void* ldst) {
    __builtin_amdgcn_global_load_lds((const __attribute__((address_space(1))) uint32_t*)gsrc,
                                     (__attribute__((address_space(3))) uint32_t*)ldst,
                                     16, 0, 0);
}

// ============ FAST K1: fused prep (round-7 proven) ============
// blocks [0,512): gate GEMM split-K=4 -> part[sl][tok][e]; writes xf16 for its
//                 own x slice; block 0 zeroes counts.
// blocks [512,2560): We [e][k][n] f32 -> WeT [e][n][k] f16 (LDS transpose).
__global__ __launch_bounds__(256) void k_prep(const float* __restrict__ x,
                                              const float* __restrict__ Wg,
                                              const float* __restrict__ We,
                                              float* __restrict__ part,
                                              int* __restrict__ counts,
                                              _Float16* __restrict__ xf16,
                                              _Float16* __restrict__ WeT) {
    __shared__ float xs[64 * 68];
    __shared__ float wgs[64 * 32];
    const int t = threadIdx.x;

    if (blockIdx.x >= 512) {
        const int cb = blockIdx.x - 512;
        const int e  = cb >> 6;
        const int kt = (cb >> 3) & 7, nt = cb & 7;
        const int k0 = kt * 64, n0 = nt * 64;
        const float* src = We + ((size_t)e * NIN + k0) * NOUTD + n0;
#pragma unroll
        for (int i = 0; i < 4; i++) {
            int idx = t + i * 256;           // 0..1023
            int k = idx >> 4, nq = idx & 15;
            float4 v = *(const float4*)&src[(size_t)k * NOUTD + nq * 4];
            *(float4*)&xs[k * 68 + nq * 4] = v;
        }
        __syncthreads();
        const int n = t >> 2, ks = (t & 3) * 16;
        half8 h0, h1;
#pragma unroll
        for (int j = 0; j < 8; j++) h0[j] = (_Float16)xs[(ks + j) * 68 + n];
#pragma unroll
        for (int j = 0; j < 8; j++) h1[j] = (_Float16)xs[(ks + 8 + j) * 68 + n];
        _Float16* dst = WeT + ((size_t)e * NOUTD + n0 + n) * NIN + k0 + ks;
        *(half8*)&dst[0] = h0;
        *(half8*)&dst[8] = h1;
        return;
    }

    if (blockIdx.x == 0 && t < 64) counts[t] = 0;
    const int tt = blockIdx.x >> 2, sl = blockIdx.x & 3;
    const int b0 = tt * 64;
    const int kbase = sl * 128;
    const int tok = t >> 2;
    const int eg  = (t & 3) * 8;

    float acc[8];
#pragma unroll
    for (int i = 0; i < 8; i++) acc[i] = 0.f;

    for (int ksi = 0; ksi < 2; ksi++) {
        const int k0 = kbase + ksi * 64;
#pragma unroll
        for (int i = 0; i < 4; i++) {
            int idx = t + i * 256;
            int tr = idx >> 4, kq = idx & 15;
            float4 v = *(const float4*)&x[(size_t)(b0 + tr) * NIN + k0 + kq * 4];
            *(float4*)&xs[tr * 68 + kq * 4] = v;
            half4 hv = {(_Float16)v.x, (_Float16)v.y, (_Float16)v.z, (_Float16)v.w};
            *(half4*)&xf16[(size_t)(b0 + tr) * NIN + k0 + kq * 4] = hv;
        }
#pragma unroll
        for (int i = 0; i < 2; i++) {
            int idx = t + i * 256;
            int r = idx >> 3, cq = idx & 7;
            float4 v = *(const float4*)&Wg[(size_t)(k0 + r) * NEXP + cq * 4];
            *(float4*)&wgs[r * 32 + cq * 4] = v;
        }
        __syncthreads();
#pragma unroll
        for (int kk = 0; kk < 64; kk++) {
            float a = xs[tok * 68 + kk];
            float4 b1 = *(const float4*)&wgs[kk * 32 + eg];
            float4 b2 = *(const float4*)&wgs[kk * 32 + eg + 4];
            acc[0] = fmaf(a, b1.x, acc[0]);
            acc[1] = fmaf(a, b1.y, acc[1]);
            acc[2] = fmaf(a, b1.z, acc[2]);
            acc[3] = fmaf(a, b1.w, acc[3]);
            acc[4] = fmaf(a, b2.x, acc[4]);
            acc[5] = fmaf(a, b2.y, acc[5]);
            acc[6] = fmaf(a, b2.z, acc[6]);
            acc[7] = fmaf(a, b2.w, acc[7]);
        }
        __syncthreads();
    }
    float4 o1 = {acc[0], acc[1], acc[2], acc[3]};
    float4 o2 = {acc[4], acc[5], acc[6], acc[7]};
    size_t ob = ((size_t)sl * B_TOK + b0 + tok) * NEXP + eg;
    *(float4*)&part[ob] = o1;
    *(float4*)&part[ob + 4] = o2;
}

// ============ FAST K2: sum partials + softmax + top2 + scatter + aux ============
// 64 blocks x 128 tokens
__global__ __launch_bounds__(256) void k_top2_route(const float* __restrict__ part,
                                                    const float* __restrict__ bg,
                                                    int* __restrict__ counts,
                                                    int* __restrict__ gtok,
                                                    float* __restrict__ gw,
                                                    float* __restrict__ aux) {
    __shared__ float sacc[128 * 33];
    __shared__ int lc[64];
    __shared__ int lbase[64];
    const int t = threadIdx.x;
    const int b0 = blockIdx.x * 128;
    if (blockIdx.x == 0 && t == 0) aux[0] = 0.0f;

    for (int sl = 0; sl < 4; sl++) {
#pragma unroll
        for (int i = 0; i < 4; i++) {
            int idx = t + i * 256;            // 0..1023
            int tok = idx >> 3, ef = (idx & 7) * 4;
            float4 v = *(const float4*)&part[((size_t)sl * B_TOK + b0 + tok) * NEXP + ef];
            float* d = &sacc[tok * 33 + ef];
            if (sl == 0) { d[0] = v.x; d[1] = v.y; d[2] = v.z; d[3] = v.w; }
            else         { d[0] += v.x; d[1] += v.y; d[2] += v.z; d[3] += v.w; }
        }
    }
    if (t < 64) lc[t] = 0;
    __syncthreads();

    float w0 = 0.f, w1 = 0.f;
    int i0 = 0, i1 = 0;
    const bool act = t < 128;
    if (act) {
        float v[32];
#pragma unroll
        for (int e = 0; e < NEXP; e++) v[e] = sacc[t * 33 + e] + bg[e];
        float m = v[0];
#pragma unroll
        for (int e = 1; e < NEXP; e++) m = fmaxf(m, v[e]);
        float s = 0.f;
        float v0 = -3.0e38f, v1 = -3.0e38f;
#pragma unroll
        for (int e = 0; e < NEXP; e++) {
            float val = v[e];
            s += expf(val - m);
            if (val > v0) { v1 = v0; i1 = i0; v0 = val; i0 = e; }
            else if (val > v1) { v1 = val; i1 = e; }
        }
        float inv = 1.f / s;
        w0 = expf(v0 - m) * inv;
        w1 = expf(v1 - m) * inv;
    }
    int r0 = 0, r1 = 0;
    if (act) {
        r0 = atomicAdd(&lc[i0], 1);
        r1 = atomicAdd(&lc[32 + i1], 1);
    }
    __syncthreads();
    if (t < 64) lbase[t] = (lc[t] > 0) ? atomicAdd(&counts[t], lc[t]) : 0;
    __syncthreads();
    if (act) {
        int p0 = lbase[i0] + r0;
        int p1 = lbase[32 + i1] + r1;
        gtok[i0 * B_TOK + p0] = b0 + t;          gw[i0 * B_TOK + p0] = w0;
        gtok[(32 + i1) * B_TOK + p1] = b0 + t;   gw[(32 + i1) * B_TOK + p1] = w1;
    }
}

// ============ FAST K3/K4: grouped expert GEMM, MFMA f16, 128x64 tile, BK=64 ============
// 512 threads, 8 waves (4 row x 2 col); each wave computes 32 tok x 32 n.
// ~49.5KB LDS -> 3 blocks/CU; ntiles ~540/round -> ~2.1 blocks/CU resident.
// LDS rows are 64 f16 (8 x 16B slots), XOR-swizzled: slot' = slot ^ (row&7).
// Bijective XCD-chunked tile mapping; 8 consecutive tiles share one A-panel.
template <int ACC>
__global__ __launch_bounds__(512) void k_expert16(const _Float16* __restrict__ xf16,
                                                  const _Float16* __restrict__ WeT,
                                                  const float* __restrict__ be,
                                                  const int* __restrict__ counts,
                                                  const int* __restrict__ gtok,
                                                  const float* __restrict__ gw,
                                                  float* __restrict__ out,
                                                  int round) {
    __shared__ _Float16 sA[2][128 * 64];   // 16 KB per buf
    __shared__ _Float16 sB[2][64 * 64];    // 8 KB per buf
    __shared__ int   stok[128];
    __shared__ float sw[128];
    __shared__ float sbe[64];
    __shared__ int   pfx[33];

    const int t = threadIdx.x;
    const int lane = t & 63, wid = t >> 6;          // 8 waves
    const int wr = wid >> 1, wc = wid & 1;          // 4 x 2
    const int g = lane >> 4, c16 = lane & 15;

    if (t == 0) {
        int a = 0;
#pragma unroll
        for (int e = 0; e < NEXP; e++) { pfx[e] = a; a += (counts[round * 32 + e] + 127) >> 7; }
        pfx[32] = a;
    }
    __syncthreads();
    const int ntiles = pfx[32] * 8;

    {
        const int xcd = blockIdx.x & 7, pos = blockIdx.x >> 3;
        const int q = ntiles >> 3, r = ntiles & 7;
        const int cterr = q + (xcd < r ? 1 : 0);
        if (pos >= cterr) return;
        const int start = (xcd < r) ? xcd * (q + 1) : r * (q + 1) + (xcd - r) * q;
        const int tile = start + pos;

        const int rt = tile >> 3, ct = tile & 7, nb = ct * 64;
        int e = 0;
        while (pfx[e + 1] <= rt) e++;
        const int jt = rt - pfx[e];
        const int cnt = counts[round * 32 + e];
        const int base = (round * 32 + e) * B_TOK + jt * 128;
        const int valid = min(128, cnt - jt * 128);

        if (t < 128) {
            int rr = min(t, valid - 1);
            stok[t] = gtok[base + rr];
            sw[t]   = gw[base + rr];
        }
        if (t < 64) sbe[t] = be[e * NOUTD + nb + t];
        __syncthreads();

        f32x4 acc[2][2];
#pragma unroll
        for (int m = 0; m < 2; m++)
#pragma unroll
            for (int n = 0; n < 2; n++) acc[m][n] = (f32x4){0.f, 0.f, 0.f, 0.f};

        const _Float16* WB = WeT + ((size_t)e * NOUTD + nb) * NIN;

        // A staging: 2 row-blocks of 8 rows per wave (rows wid*16 .. wid*16+15).
        const int r0a = wid * 16 + (lane >> 3);
        const int r1a = r0a + 8;
        const int ss0 = (lane & 7) ^ (r0a & 7);
        const int ss1 = (lane & 7) ^ (r1a & 7);
        // B staging: 1 row-block of 8 rows per wave (rows wid*8 .. wid*8+7).
        const int rB  = wid * 8 + (lane >> 3);
        const int ssB = (lane & 7) ^ (rB & 7);

#define STAGE_AB(buf, kofs)                                                        \
        gload_lds16(xf16 + (size_t)stok[r0a] * NIN + (kofs) + ss0 * 8,             \
                    &sA[buf][(wid * 16) * 64]);                                    \
        gload_lds16(xf16 + (size_t)stok[r1a] * NIN + (kofs) + ss1 * 8,             \
                    &sA[buf][(wid * 16 + 8) * 64]);                                \
        gload_lds16(WB + (size_t)rB * NIN + (kofs) + ssB * 8,                      \
                    &sB[buf][(wid * 8) * 64]);

        STAGE_AB(0, 0)
        __syncthreads();

        int cur = 0;
        for (int k0 = 0; k0 < NIN; k0 += 64) {
            if (k0 + 64 < NIN) {
                if (cur == 0) { STAGE_AB(1, k0 + 64) }
                else          { STAGE_AB(0, k0 + 64) }
            }

            half8 fa[2][2], fb[2][2];
#pragma unroll
            for (int ks = 0; ks < 2; ks++) {
#pragma unroll
                for (int m = 0; m < 2; m++) {
                    int ar = wr * 32 + m * 16 + c16;
                    fa[ks][m] = *(const half8*)&sA[cur][ar * 64 + (((ks * 4 + g) ^ (ar & 7)) * 8)];
                }
#pragma unroll
                for (int n = 0; n < 2; n++) {
                    int br = wc * 32 + n * 16 + c16;
                    fb[ks][n] = *(const half8*)&sB[cur][br * 64 + (((ks * 4 + g) ^ (br & 7)) * 8)];
                }
            }
#pragma unroll
            for (int ks = 0; ks < 2; ks++)
#pragma unroll
                for (int m = 0; m < 2; m++)
#pragma unroll
                    for (int n = 0; n < 2; n++)
                        acc[m][n] = __builtin_amdgcn_mfma_f32_16x16x32_f16(fa[ks][m], fb[ks][n], acc[m][n], 0, 0, 0);
            __syncthreads();
            cur ^= 1;
        }
#undef STAGE_AB

#pragma unroll
        for (int m = 0; m < 2; m++) {
#pragma unroll
            for (int q2 = 0; q2 < 4; q2++) {
                int lr = wr * 32 + m * 16 + g * 4 + q2;
                if (lr < valid) {
                    float w = sw[lr];
                    size_t ob = (size_t)stok[lr] * NOUTD + nb + wc * 32 + c16;
#pragma unroll
                    for (int n = 0; n < 2; n++) {
                        float v = fmaxf(acc[m][n][q2] + sbe[wc * 32 + n * 16 + c16], 0.f) * w;
                        float* op = &out[ob + n * 16];
                        if (ACC) v += *op;
                        *op = v;
                    }
                }
            }
        }
    }
}

// =====================================================================
// ==================== fallback (round-1, fp32) path ==================
// =====================================================================
__global__ __launch_bounds__(256) void k_gate(const float* __restrict__ x,
                                              const float* __restrict__ Wg,
                                              const float* __restrict__ bg,
                                              float* __restrict__ logits) {
    __shared__ float xs[64 * 68];
    __shared__ float wgs[64 * 32];
    const int t = threadIdx.x;
    const int b0 = blockIdx.x * 64;
    const int tok = t >> 2;
    const int eg  = (t & 3) * 8;
    float acc[8];
#pragma unroll
    for (int i = 0; i < 8; i++) acc[i] = 0.f;
    for (int k0 = 0; k0 < NIN; k0 += 64) {
#pragma unroll
        for (int i = 0; i < 4; i++) {
            int idx = t + i * 256;
            int tr = idx >> 4, kq = idx & 15;
            float4 v = *(const float4*)&x[(size_t)(b0 + tr) * NIN + k0 + kq * 4];
            *(float4*)&xs[tr * 68 + kq * 4] = v;
        }
#pragma unroll
        for (int i = 0; i < 2; i++) {
            int idx = t + i * 256;
            int r = idx >> 3, cq = idx & 7;
            float4 v = *(const float4*)&Wg[(size_t)(k0 + r) * NEXP + cq * 4];
            *(float4*)&wgs[r * 32 + cq * 4] = v;
        }
        __syncthreads();
#pragma unroll
        for (int kk = 0; kk < 64; kk++) {
            float a = xs[tok * 68 + kk];
            float4 b1 = *(const float4*)&wgs[kk * 32 + eg];
            float4 b2 = *(const float4*)&wgs[kk * 32 + eg + 4];
            acc[0] = fmaf(a, b1.x, acc[0]);
            acc[1] = fmaf(a, b1.y, acc[1]);
            acc[2] = fmaf(a, b1.z, acc[2]);
            acc[3] = fmaf(a, b1.w, acc[3]);
            acc[4] = fmaf(a, b2.x, acc[4]);
            acc[5] = fmaf(a, b2.y, acc[5]);
            acc[6] = fmaf(a, b2.z, acc[6]);
            acc[7] = fmaf(a, b2.w, acc[7]);
        }
        __syncthreads();
    }
    float4 o1, o2;
    o1.x = acc[0] + bg[eg + 0]; o1.y = acc[1] + bg[eg + 1];
    o1.z = acc[2] + bg[eg + 2]; o1.w = acc[3] + bg[eg + 3];
    o2.x = acc[4] + bg[eg + 4]; o2.y = acc[5] + bg[eg + 5];
    o2.z = acc[6] + bg[eg + 6]; o2.w = acc[7] + bg[eg + 7];
    size_t ob = (size_t)(b0 + tok) * NEXP + eg;
    *(float4*)&logits[ob] = o1;
    *(float4*)&logits[ob + 4] = o2;
}

__global__ __launch_bounds__(256) void k_top2(const float* __restrict__ logits,
                                              int* __restrict__ tkidx,
                                              float* __restrict__ tkw,
                                              int* __restrict__ counts) {
    __shared__ int lc[64];
    const int t = threadIdx.x;
    const int b = blockIdx.x * 256 + t;
    if (t < 64) lc[t] = 0;
    __syncthreads();
    float v[32];
#pragma unroll
    for (int i = 0; i < 8; i++) {
        float4 q = *(const float4*)&logits[(size_t)b * NEXP + i * 4];
        v[i * 4 + 0] = q.x; v[i * 4 + 1] = q.y; v[i * 4 + 2] = q.z; v[i * 4 + 3] = q.w;
    }
    float m = v[0];
#pragma unroll
    for (int e = 1; e < NEXP; e++) m = fmaxf(m, v[e]);
    float s = 0.f;
#pragma unroll
    for (int e = 0; e < NEXP; e++) s += expf(v[e] - m);
    float v0 = -3.0e38f, v1 = -3.0e38f;
    int i0 = 0, i1 = 0;
#pragma unroll
    for (int e = 0; e < NEXP; e++) {
        float val = v[e];
        if (val > v0) { v1 = v0; i1 = i0; v0 = val; i0 = e; }
        else if (val > v1) { v1 = val; i1 = e; }
    }
    float inv = 1.f / s;
    tkidx[b * 2 + 0] = i0; tkidx[b * 2 + 1] = i1;
    tkw[b * 2 + 0] = expf(v0 - m) * inv; tkw[b * 2 + 1] = expf(v1 - m) * inv;
    atomicAdd(&lc[i0], 1);
    atomicAdd(&lc[32 + i1], 1);
    __syncthreads();
    if (t < 64 && lc[t] > 0) atomicAdd(&counts[t], lc[t]);
}

__global__ __launch_bounds__(64) void k_build(const int* __restrict__ counts,
                                              int* __restrict__ offs,
                                              int* __restrict__ curs,
                                              int2* __restrict__ tiles,
                                              int* __restrict__ tilec,
                                              float* __restrict__ aux) {
    __shared__ int c[64];
    __shared__ int o[64];
    const int t = threadIdx.x;
    c[t] = counts[t];
    __syncthreads();
    if (t == 0) {
        int off = 0;
        for (int i = 0; i < 64; i++) {
            if ((i & 31) == 0) off = 0;
            o[i] = off;
            off += c[i];
        }
        aux[0] = 0.0f;
    }
    __syncthreads();
    offs[t] = o[t];
    curs[t] = o[t];
    if (t < 2) {
        int tc = 0;
        for (int e = 0; e < NEXP; e++) {
            int cnt = c[t * 32 + e];
            int nt = (cnt + 63) >> 6;
            for (int j = 0; j < nt; j++) tiles[t * 256 + tc++] = make_int2(e, j);
        }
        tilec[t] = tc;
    }
}

__global__ __launch_bounds__(256) void k_scatter(const int* __restrict__ tkidx,
                                                 const float* __restrict__ tkw,
                                                 int* __restrict__ curs,
                                                 int* __restrict__ gtok,
                                                 float* __restrict__ gw) {
    __shared__ int lc[64];
    __shared__ int lbase[64];
    const int t = threadIdx.x;
    const int b = blockIdx.x * 256 + t;
    if (t < 64) lc[t] = 0;
    __syncthreads();
    int i0 = tkidx[b * 2 + 0], i1 = tkidx[b * 2 + 1];
    int r0 = atomicAdd(&lc[i0], 1);
    int r1 = atomicAdd(&lc[32 + i1], 1);
    __syncthreads();
    if (t < 64) lbase[t] = (lc[t] > 0) ? atomicAdd(&curs[t], lc[t]) : 0;
    __syncthreads();
    int p0 = lbase[i0] + r0;
    int p1 = lbase[32 + i1] + r1;
    gtok[p0] = b;          gw[p0] = tkw[b * 2 + 0];
    gtok[8192 + p1] = b;   gw[8192 + p1] = tkw[b * 2 + 1];
}

template <int ACC>
__global__ __launch_bounds__(256) void k_expert(const float* __restrict__ x,
                                                const float* __restrict__ We,
                                                const float* __restrict__ be,
                                                const int* __restrict__ counts,
                                                const int* __restrict__ offs,
                                                const int2* __restrict__ tiles,
                                                const int* __restrict__ tilec,
                                                const int* __restrict__ gtok,
                                                const float* __restrict__ gw,
                                                float* __restrict__ out,
                                                int round) {
    __shared__ float xsT[32 * 68];
    __shared__ float wsd[32 * 64];
    __shared__ int   stok[64];
    __shared__ float sw[64];
    const int t = threadIdx.x;
    const int tx = t & 15, ty = t >> 4;
    const int ntiles = tilec[round] * 8;
    for (int tile = blockIdx.x; tile < ntiles; tile += gridDim.x) {
        int rt = tile >> 3, ct = tile & 7;
        int2 td = tiles[round * 256 + rt];
        int e = td.x, jt = td.y;
        int cnt = counts[round * 32 + e];
        int base = offs[round * 32 + e] + jt * 64;
        int valid = min(64, cnt - jt * 64);
        if (t < 64) {
            int rr = min(t, valid - 1);
            stok[t] = gtok[round * 8192 + base + rr];
            sw[t]   = gw  [round * 8192 + base + rr];
        }
        __syncthreads();
        float acc[16];
#pragma unroll
        for (int i = 0; i < 16; i++) acc[i] = 0.f;
        const float* Wb = We + (size_t)e * NIN * NOUTD + ct * 64;
        for (int k0 = 0; k0 < NIN; k0 += 32) {
#pragma unroll
            for (int i = 0; i < 2; i++) {
                int idx = t + i * 256;
                int tr = idx >> 3, kq = idx & 7;
                float4 v = *(const float4*)&x[(size_t)stok[tr] * NIN + k0 + kq * 4];
                xsT[(kq * 4 + 0) * 68 + tr] = v.x;
                xsT[(kq * 4 + 1) * 68 + tr] = v.y;
                xsT[(kq * 4 + 2) * 68 + tr] = v.z;
                xsT[(kq * 4 + 3) * 68 + tr] = v.w;
            }
#pragma unroll
            for (int i = 0; i < 2; i++) {
                int idx = t + i * 256;
                int r = idx >> 4, cq = idx & 15;
                *(float4*)&wsd[r * 64 + cq * 4] =
                    *(const float4*)&Wb[(size_t)(k0 + r) * NOUTD + cq * 4];
            }
            __syncthreads();
#pragma unroll
            for (int kk = 0; kk < 32; kk++) {
                float4 a  = *(const float4*)&xsT[kk * 68 + ty * 4];
                float4 bv = *(const float4*)&wsd[kk * 64 + tx * 4];
                float av[4] = {a.x, a.y, a.z, a.w};
                float bb[4] = {bv.x, bv.y, bv.z, bv.w};
#pragma unroll
                for (int i = 0; i < 4; i++)
#pragma unroll
                    for (int j = 0; j < 4; j++)
                        acc[i * 4 + j] = fmaf(av[i], bb[j], acc[i * 4 + j]);
            }
            __syncthreads();
        }
#pragma unroll
        for (int i = 0; i < 4; i++) {
            int row = ty * 4 + i;
            if (jt * 64 + row < cnt) {
                float w = sw[row];
                float4 bb = *(const float4*)&be[(size_t)e * NOUTD + ct * 64 + tx * 4];
                float4 o;
                o.x = w * fmaxf(acc[i * 4 + 0] + bb.x, 0.f);
                o.y = w * fmaxf(acc[i * 4 + 1] + bb.y, 0.f);
                o.z = w * fmaxf(acc[i * 4 + 2] + bb.z, 0.f);
                o.w = w * fmaxf(acc[i * 4 + 3] + bb.w, 0.f);
                float* op = &out[(size_t)stok[row] * NOUTD + ct * 64 + tx * 4];
                if (ACC) {
                    float4 p = *(const float4*)op;
                    o.x += p.x; o.y += p.y; o.z += p.z; o.w += p.w;
                }
                *(float4*)op = o;
            }
        }
        __syncthreads();
    }
}

extern "C" void kernel_launch(void* const* d_in, const int* in_sizes, int n_in,
                              void* d_out, int out_size, void* d_ws, size_t ws_size,
                              hipStream_t stream) {
    const float* x  = (const float*)d_in[0];
    const float* Wg = (const float*)d_in[1];
    const float* bg = (const float*)d_in[2];
    const float* We = (const float*)d_in[3];
    const float* be = (const float*)d_in[4];
    float* out = (float*)d_out;
    char* ws = (char*)d_ws;

    if (ws_size >= F_NEED) {
        _Float16* xf16 = (_Float16*)(ws + F_XF16);
        _Float16* WeT  = (_Float16*)(ws + F_WET);
        float* part    = (float*)(ws + F_PART);
        int*   counts  = (int*)(ws + F_CNT);
        int*   gtok    = (int*)(ws + F_GTOK);
        float* gw      = (float*)(ws + F_GW);

        k_prep<<<2560, 256, 0, stream>>>(x, Wg, We, part, counts, xf16, WeT);
        k_top2_route<<<64, 256, 0, stream>>>(part, bg, counts, gtok, gw,
                                             out + (size_t)B_TOK * NOUTD);
        k_expert16<0><<<768, 512, 0, stream>>>(xf16, WeT, be, counts, gtok, gw, out, 0);
        k_expert16<1><<<768, 512, 0, stream>>>(xf16, WeT, be, counts, gtok, gw, out, 1);
    } else {
        float* logits = (float*)(ws + WS_LOGITS);
        int*   tkidx  = (int*)(ws + WS_TKIDX);
        float* tkw    = (float*)(ws + WS_TKW);
        int*   counts = (int*)(ws + WS_CTRS);
        int*   curs   = (int*)(ws + WS_CURS);
        int*   tilec  = (int*)(ws + WS_TILEC);
        int*   offsp  = (int*)(ws + WS_OFFS);
        int2*  tiles  = (int2*)(ws + WS_TILES);
        int*   gtok   = (int*)(ws + WS_GTOK);
        float* gw     = (float*)(ws + WS_GW);

        (void)hipMemsetAsync(ws + WS_CTRS, 0, 256, stream);
        k_gate<<<128, 256, 0, stream>>>(x, Wg, bg, logits);
        k_top2<<<32, 256, 0, stream>>>(logits, tkidx, tkw, counts);
        k_build<<<1, 64, 0, stream>>>(counts, offsp, curs, tiles, tilec,
                                      out + (size_t)B_TOK * NOUTD);
        k_scatter<<<32, 256, 0, stream>>>(tkidx, tkw, curs, gtok, gw);
        k_expert<0><<<1280, 256, 0, stream>>>(x, We, be, counts, offsp, tiles, tilec,
                                              gtok, gw, out, 0);
        k_expert<1><<<1280, 256, 0, stream>>>(x, We, be, counts, offsp, tiles, tilec,
                                              gtok, gw, out, 1);
    }
}